// Round 6
// baseline (19978.154 us; speedup 1.0000x reference)
//
#include <hip/hip_runtime.h>

// =====================================================================
// LSTM autoencoder v11 (resubmission — round-5 bench was an MI355X
// container infra failure; kernel re-audited for hang/race hazards,
// none found; source identical to round-4 submission).
//
// v10 dual-chain + DPP reductions, plus:
//  (1) all-wave polling wait: every wave polls the 32 chain flags and
//      begins its share of the h-stage immediately; one __syncthreads
//      per phase instead of two, and no wave0-poll->broadcast stall.
//  (2) weight chunk-0 register prefetch (8 x float4 = 32 VGPR) issued
//      before the wait; consumed by BOTH chains (A and B phases of the
//      same type use identical weights) -> post-barrier L2 cold-start
//      hidden under wait+stage, twice per prefetch.
// Everything else (barriers, packing, LDS layout NR=12, DPP reduce)
// identical to v10. v8-style fallback kernel retained.
// =====================================================================

#define Bsz 128
#define Tsz 128
#define Fsz 128
#define Dsz 512
#define ND  2048
#define NBLK 256
#define NTHR 1024

// ---- ws layout (float offsets) ----
#define OFF_HT0  1024
#define OFF_HT1  (OFF_HT0 + Dsz*Bsz)
#define OFF_HMT  (OFF_HT1 + Dsz*Bsz)
#define OFF_WEND (OFF_HMT + Dsz*Bsz)
// packed weights (gate-interleaved float4: Wp4[dcol*K + k] = {i,f,g,o})
#define OFF_P_EW0   OFF_WEND
#define OFF_P_EU0   (OFF_P_EW0 + Fsz*ND)
#define OFF_P_WSUM  (OFF_P_EU0 + Dsz*ND)
#define OFF_P_WDECA (OFF_P_WSUM + Dsz*ND)
#define OFF_P_DW0   (OFF_P_WDECA + Dsz*ND)
#define OFF_P_DU0   (OFF_P_DW0 + Fsz*ND)
#define OFF_P_DW1   (OFF_P_DU0 + Dsz*ND)
#define OFF_P_DU1   (OFF_P_DW1 + Dsz*ND)
#define OFF_P_BF    (OFF_P_DU1 + Dsz*ND)
#define OFF_P_DWT   (OFF_P_BF + ND)
#define WS_PACKED_FLOATS (OFF_P_DWT + Dsz*Fsz)
// fallback layout
#define OFF_F_WSUM  OFF_WEND
#define OFF_F_WDECA (OFF_F_WSUM + Dsz*ND)
#define OFF_F_BF    (OFF_F_WDECA + Dsz*ND)
#define OFF_F_DWT   (OFF_F_BF + ND)
#define WS_FALLBACK_FLOATS (OFF_F_DWT + Dsz*Fsz)

#define NR 12   // LDS row stride: 8 data + 4 pad floats (16B aligned)

__device__ __forceinline__ float sigf(float x) {
    return 1.0f / (1.0f + __expf(-x));
}
__device__ __forceinline__ float ld_coh(const float* p) {
    return __hip_atomic_load((float*)p, __ATOMIC_RELAXED, __HIP_MEMORY_SCOPE_AGENT);
}
__device__ __forceinline__ void st_coh(float* p, float v) {
    __hip_atomic_store(p, v, __ATOMIC_RELAXED, __HIP_MEMORY_SCOPE_AGENT);
}

// ---- split group barrier (32 members, per-chain slot arrays) ----
__device__ __forceinline__ void arrive(unsigned* slot, unsigned ep) {
    __syncthreads();   // all waves' compute + coherent stores drained
    if (threadIdx.x == 0)
        __hip_atomic_store(slot, ep, __ATOMIC_RELEASE, __HIP_MEMORY_SCOPE_AGENT);
}
// all-wave poll: every wave spins on the 32 flags itself; NO syncthreads.
// Caller stages its share right after, then one __syncthreads before consume.
__device__ __forceinline__ void wait_all(unsigned* gslots, unsigned ep) {
    const int l = (int)threadIdx.x & 63;
    for (;;) {
        unsigned v = (l < 32)
            ? __hip_atomic_load(&gslots[l], __ATOMIC_RELAXED,
                                __HIP_MEMORY_SCOPE_AGENT)
            : ep;
        if (__all(v >= ep)) break;
        __builtin_amdgcn_s_sleep(1);
    }
}
__device__ __forceinline__ void gbar_all(unsigned* slots, int blkid, unsigned ep) {
    __syncthreads();
    if (threadIdx.x == 0) {
        __threadfence();
        __hip_atomic_store(&slots[blkid], ep, __ATOMIC_RELEASE,
                           __HIP_MEMORY_SCOPE_AGENT);
    }
    if (threadIdx.x < 64) {
        for (;;) {
            unsigned mn = ~0u;
            #pragma unroll
            for (int q = 0; q < 4; ++q) {
                unsigned v = __hip_atomic_load(&slots[threadIdx.x * 4 + q],
                                               __ATOMIC_RELAXED, __HIP_MEMORY_SCOPE_AGENT);
                mn = min(mn, v);
            }
            if (__all(mn >= ep)) break;
            __builtin_amdgcn_s_sleep(1);
        }
        if (threadIdx.x == 0) __threadfence();
    }
    __syncthreads();
}

// ---- P0 packing (identical to v6..v10) ----
__device__ void pack_gate(float* dst, const float* src, int K, int kshift, int gid) {
    const int total = K * Dsz;
    for (int u = gid; u < total; u += NBLK * NTHR) {
        const int dd = u >> kshift;
        const int k = u & (K - 1);
        const float* sp = src + (size_t)k * ND + dd;
        ((float4*)dst)[u] = make_float4(sp[0], sp[Dsz], sp[2 * Dsz], sp[3 * Dsz]);
    }
}
__device__ void pack_wsum(float* dst, const float* a, const float* bsrc, int gid) {
    for (int u = gid; u < Dsz * Dsz; u += NBLK * NTHR) {
        const int dd = u >> 9, k = u & 511;
        const float* pa = a + (size_t)k * ND + dd;
        const float* pb = bsrc + (size_t)k * ND + dd;
        ((float4*)dst)[u] = make_float4(pa[0] + pb[0], pa[Dsz] + pb[Dsz],
                                        pa[2*Dsz] + pb[2*Dsz], pa[3*Dsz] + pb[3*Dsz]);
    }
}
__device__ void pack_wdeca_p(float* dst, const float* dU0, const float* dW0,
                             const float* dw, int gid) {
    for (int u = gid; u < Dsz * Dsz; u += NBLK * NTHR) {
        const int dd = u >> 9, k = u & 511;
        const float* pu = dU0 + (size_t)k * ND + dd;
        float a0 = pu[0], a1 = pu[Dsz], a2 = pu[2*Dsz], a3 = pu[3*Dsz];
        const float* dwr = dw + k * Fsz;
        for (int j = 0; j < Fsz; ++j) {
            const float wv = dwr[j];
            const float* dr = dW0 + (size_t)j * ND + dd;
            a0 += wv * dr[0]; a1 += wv * dr[Dsz];
            a2 += wv * dr[2*Dsz]; a3 += wv * dr[3*Dsz];
        }
        ((float4*)dst)[u] = make_float4(a0, a1, a2, a3);
    }
}

// =====================================================================
// ======================  v11 kernel  =================================
// =====================================================================

// stage 512 h rows (8 samples) from transposed coherent buffer
__device__ __forceinline__ void stageH9(float* XL, const float* HTsrc, int sr, int rbase) {
    #pragma unroll
    for (int ii = 0; ii < 4; ++ii) {
        const int i = (int)threadIdx.x + ii * NTHR;
        const int r = i >> 3, bb = i & 7;
        XL[(rbase + r) * NR + bb] = ld_coh(HTsrc + (size_t)r * Bsz + sr + bb);
    }
}
// stage 128 x rows (8 samples), 1 elem/thread
__device__ __forceinline__ void stageX9(float* XL, const float* src, int sr, int rbase) {
    const int r = (int)threadIdx.x & 127, bb = (int)threadIdx.x >> 7;
    XL[(rbase + r) * NR + bb] = src[(size_t)(sr + bb) * (Tsz * Fsz) + r];
}

#define FMA16(A0,A1,A2,A3,x4,w4) \
    A0.x += x4.x*w4.x; A0.y += x4.x*w4.y; A0.z += x4.x*w4.z; A0.w += x4.x*w4.w; \
    A1.x += x4.y*w4.x; A1.y += x4.y*w4.y; A1.z += x4.y*w4.z; A1.w += x4.y*w4.w; \
    A2.x += x4.z*w4.x; A2.y += x4.z*w4.y; A2.z += x4.z*w4.z; A2.w += x4.z*w4.w; \
    A3.x += x4.w*w4.x; A3.y += x4.w*w4.y; A3.z += x4.w*w4.z; A3.w += x4.w*w4.w;

// prefetch first 8 weight rows (chunk0) into registers
__device__ __forceinline__ void pref8(float4 P[8], const float4* __restrict__ Wp) {
    #pragma unroll
    for (int j = 0; j < 8; ++j) P[j] = Wp[j * 32];
}

// consume NJ*32 K-rows; plain (streamed weights)
template<int NJ>
__device__ __forceinline__ void consTv(const float4* __restrict__ Wp,
        const float* __restrict__ Xb,
        float4& A0, float4& A1, float4& A2, float4& A3)
{
    #pragma unroll 8
    for (int j = 0; j < NJ; ++j) {
        const float4 x4 = *(const float4*)(Xb + j * (32 * NR));
        const float4 w4 = Wp[j * 32];
        FMA16(A0, A1, A2, A3, x4, w4)
    }
}
// consume with register-prefetched chunk0 (j<8 from P)
template<int NJ>
__device__ __forceinline__ void consTvP(const float4 P[8],
        const float4* __restrict__ Wp, const float* __restrict__ Xb,
        float4& A0, float4& A1, float4& A2, float4& A3)
{
    #pragma unroll
    for (int j = 0; j < NJ; ++j) {
        const float4 x4 = *(const float4*)(Xb + j * (32 * NR));
        const float4 w4 = (j < 8) ? P[j] : Wp[j * 32];
        FMA16(A0, A1, A2, A3, x4, w4)
    }
}

// ---- cheap cross-lane reduction (identical to v10) ----
__device__ __forceinline__ float dppx1(float v) {   // xor 1
    return v + __int_as_float(__builtin_amdgcn_mov_dpp(
        __float_as_int(v), 0xB1, 0xf, 0xf, true));
}
__device__ __forceinline__ float dppx2(float v) {   // xor 2
    return v + __int_as_float(__builtin_amdgcn_mov_dpp(
        __float_as_int(v), 0x4E, 0xf, 0xf, true));
}
__device__ __forceinline__ float dpphm(float v) {   // i^7 within 8
    return v + __int_as_float(__builtin_amdgcn_mov_dpp(
        __float_as_int(v), 0x141, 0xf, 0xf, true));
}
#define HXCH(lo, hi, mask, cond) { \
    float s_ = (cond) ? (lo) : (hi); \
    float r_ = __shfl_xor(s_, mask); \
    if (cond) (hi) += r_; else (lo) += r_; }

__device__ __forceinline__ float4 redZ(float4 A0, float4 A1, float4 A2, float4 A3,
                                       bool khb, bool b3b)
{
    HXCH(A0.x, A2.x, 32, khb) HXCH(A0.y, A2.y, 32, khb)
    HXCH(A0.z, A2.z, 32, khb) HXCH(A0.w, A2.w, 32, khb)
    HXCH(A1.x, A3.x, 32, khb) HXCH(A1.y, A3.y, 32, khb)
    HXCH(A1.z, A3.z, 32, khb) HXCH(A1.w, A3.w, 32, khb)
    float4 B0, B1;
    B0.x = khb ? A2.x : A0.x; B0.y = khb ? A2.y : A0.y;
    B0.z = khb ? A2.z : A0.z; B0.w = khb ? A2.w : A0.w;
    B1.x = khb ? A3.x : A1.x; B1.y = khb ? A3.y : A1.y;
    B1.z = khb ? A3.z : A1.z; B1.w = khb ? A3.w : A1.w;
    HXCH(B0.x, B1.x, 8, b3b) HXCH(B0.y, B1.y, 8, b3b)
    HXCH(B0.z, B1.z, 8, b3b) HXCH(B0.w, B1.w, 8, b3b)
    float4 Z;
    Z.x = b3b ? B1.x : B0.x; Z.y = b3b ? B1.y : B0.y;
    Z.z = b3b ? B1.z : B0.z; Z.w = b3b ? B1.w : B0.w;
    Z.x = dppx1(Z.x); Z.y = dppx1(Z.y); Z.z = dppx1(Z.z); Z.w = dppx1(Z.w);
    Z.x = dppx2(Z.x); Z.y = dppx2(Z.y); Z.z = dppx2(Z.z); Z.w = dppx2(Z.w);
    Z.x = dpphm(Z.x); Z.y = dpphm(Z.y); Z.z = dpphm(Z.z); Z.w = dpphm(Z.w);
    return Z;
}

__device__ __forceinline__ float fin4b(float4 z, const float* bias, int dcol,
                                       float cprev, float& c2o) {
    float gi = sigf(z.x + bias[dcol]);
    float gf = sigf(z.y + bias[Dsz + dcol]);
    float gg = fmaxf(z.z + bias[2 * Dsz + dcol], 0.f);
    float go = sigf(z.w + bias[3 * Dsz + dcol]);
    float c2 = gf * cprev + gi * gg;
    c2o = c2;
    return go * fmaxf(c2, 0.f);
}

// fused dense-row partials for one chain: ORED[sample][ff*4+qk]
__device__ __forceinline__ void out_part9(const float* XL, const float* DWL, float* ORED,
                                          int xo, int koff, int wv,
                                          bool khb, bool b3b, bool own, int sown)
{
    const int ff = wv & 3, qk = wv >> 2;
    float o0 = 0.f, o1 = 0.f, o2 = 0.f, o3 = 0.f;
    const float* Xb = XL + qk * 128 * NR + xo;
    const float* Wb = DWL + ff * 512 + qk * 128 + koff;
    #pragma unroll
    for (int j = 0; j < 4; ++j) {
        const float4 x4 = *(const float4*)(Xb + j * (32 * NR));
        const float w = Wb[j * 32];
        o0 += x4.x * w; o1 += x4.y * w; o2 += x4.z * w; o3 += x4.w * w;
    }
    HXCH(o0, o2, 32, khb) HXCH(o1, o3, 32, khb)
    float p0 = khb ? o2 : o0;
    float p1 = khb ? o3 : o1;
    HXCH(p0, p1, 8, b3b)
    float o = b3b ? p1 : p0;
    o = dppx1(o); o = dppx2(o); o = dpphm(o);
    if (own) ORED[sown * 16 + ff * 4 + qk] = o;
}

__global__ void __launch_bounds__(NTHR, 1)
lstm_ae_v11(const float* enc_in, const float* dec_in,
            const float* eW0, const float* eU0, const float* eb0,
            const float* eW1, const float* eU1, const float* eb1,
            const float* dW0, const float* dU0, const float* db0,
            const float* dW1, const float* dU1, const float* db1,
            const float* dw, const float* db_, float* out, float* ws)
{
    __shared__ float XLA[1024 * NR];   // 48 KB chain A
    __shared__ float XLB[1024 * NR];   // 48 KB chain B
    __shared__ float DWL[4 * 512];     //  8 KB resident dwT slice (4 fcols)
    __shared__ float OREDA[128];
    __shared__ float OREDB[128];

    unsigned* fslots = (unsigned*)ws;
    float* HT[2] = { ws + OFF_HT0, ws + OFF_HT1 };
    float* HMT = ws + OFF_HMT;

    const int blkid = blockIdx.x;
    const int grp  = blkid & 7;
    const int mem  = blkid >> 3;
    const int sgrp = mem & 7;
    const int dslc = mem >> 3;
    const int gm   = dslc * 8 + grp;
    const int chA  = sgrp * 2, chB = chA + 1;
    unsigned* gsA = (unsigned*)ws + 256 + chA * 32;
    unsigned* gsB = (unsigned*)ws + 256 + chB * 32;
    const int srA = sgrp * 16;
    const int srB = sgrp * 16 + 8;

    const int tid  = threadIdx.x;
    const int wv   = tid >> 6;
    const int lane = tid & 63;
    const int kh   = lane >> 5;
    const int qb2  = (lane >> 4) & 1;
    const int kc   = lane & 15;
    const int koff = kh * 16 + kc;
    const int dcol = grp * 64 + dslc * 16 + wv;
    const int fcol0 = grp * 16 + dslc * 4;
    const int gid  = blkid * NTHR + tid;
    const bool khb = (kh != 0);
    const bool b3b = ((kc & 8) != 0);
    const bool own = ((kc & 7) == 0);
    const int sown = qb2 * 4 + kh * 2 + ((kc >> 3) & 1);
    const int xo   = koff * NR + qb2 * 4;

    // ---- P0 ----
    pack_gate(ws + OFF_P_EW0, eW0, Fsz, 7, gid);
    pack_gate(ws + OFF_P_EU0, eU0, Dsz, 9, gid);
    pack_wsum(ws + OFF_P_WSUM, eW1, eU1, gid);
    pack_wdeca_p(ws + OFF_P_WDECA, dU0, dW0, dw, gid);
    pack_gate(ws + OFF_P_DW0, dW0, Fsz, 7, gid);
    pack_gate(ws + OFF_P_DU0, dU0, Dsz, 9, gid);
    pack_gate(ws + OFF_P_DW1, dW1, Dsz, 9, gid);
    pack_gate(ws + OFF_P_DU1, dU1, Dsz, 9, gid);
    if (gid < ND) {
        float acc = db0[gid];
        for (int j = 0; j < Fsz; ++j) acc += db_[j] * dW0[(size_t)j * ND + gid];
        (ws + OFF_P_BF)[gid] = acc;
    }
    if (gid < Dsz * Fsz) {
        const int f = gid >> 9, k = gid & 511;
        (ws + OFF_P_DWT)[(size_t)f * Dsz + k] = dw[(size_t)k * Fsz + f];
    }
    gbar_all(fslots, blkid, 1);

    // resident dwT slice
    #pragma unroll
    for (int ii = 0; ii < 2; ++ii) {
        const int i = tid + ii * NTHR;
        DWL[i] = (ws + OFF_P_DWT)[(size_t)(fcol0 + (i >> 9)) * Dsz + (i & 511)];
    }
    __syncthreads();

    const float* pBF = ws + OFF_P_BF;
    const float4* W_EW0   = (const float4*)(ws + OFF_P_EW0)   + (size_t)dcol * 128 + koff;
    const float4* W_EU0   = (const float4*)(ws + OFF_P_EU0)   + (size_t)dcol * 512 + koff;
    const float4* W_WSUM  = (const float4*)(ws + OFF_P_WSUM)  + (size_t)dcol * 512 + koff;
    const float4* W_WDECA = (const float4*)(ws + OFF_P_WDECA) + (size_t)dcol * 512 + koff;
    const float4* W_DW0   = (const float4*)(ws + OFF_P_DW0)   + (size_t)dcol * 128 + koff;
    const float4* W_DU0   = (const float4*)(ws + OFF_P_DU0)   + (size_t)dcol * 512 + koff;
    const float4* W_DW1   = (const float4*)(ws + OFF_P_DW1)   + (size_t)dcol * 512 + koff;
    const float4* W_DU1   = (const float4*)(ws + OFF_P_DU1)   + (size_t)dcol * 512 + koff;

    unsigned epA = 0, epB = 0;
    int cur = 0;
    float cA = 0.f, cmA = 0.f, cB = 0.f, cmB = 0.f;
    const float4 Z4 = make_float4(0.f, 0.f, 0.f, 0.f);
    float4 P[8];

    // ======================= encoder =======================
    for (int t = 0; t < Tsz; ++t) {
        pref8(P, W_EU0);                       // chunk0 for A-L0 AND B-L0
        stageX9(XLA, enc_in + (size_t)t * Fsz, srA, 512);
        stageX9(XLB, enc_in + (size_t)t * Fsz, srB, 512);
        __syncthreads();
        // ---- A L0 ----
        {
            float4 A0 = Z4, A1 = Z4, A2 = Z4, A3 = Z4;
            consTv<4>(W_EW0, XLA + 512 * NR + xo, A0, A1, A2, A3);
            wait_all(gsA, epA);
            stageH9(XLA, HT[cur], srA, 0);
            __syncthreads();
            consTvP<16>(P, W_EU0, XLA + xo, A0, A1, A2, A3);
            float4 Z = redZ(A0, A1, A2, A3, khb, b3b);
            if (own) {
                float cn; float h2 = fin4b(Z, eb0, dcol, cA, cn); cmA = cn;
                st_coh(&HMT[(size_t)dcol * Bsz + srA + sown], h2);
            }
            arrive(&gsA[gm], ++epA);
        }
        // ---- B L0 ----
        {
            float4 A0 = Z4, A1 = Z4, A2 = Z4, A3 = Z4;
            consTv<4>(W_EW0, XLB + 512 * NR + xo, A0, A1, A2, A3);
            wait_all(gsB, epB);
            stageH9(XLB, HT[cur], srB, 0);
            __syncthreads();
            consTvP<16>(P, W_EU0, XLB + xo, A0, A1, A2, A3);
            pref8(P, W_WSUM);                  // chunk0 for A-L1 AND B-L1
            float4 Z = redZ(A0, A1, A2, A3, khb, b3b);
            if (own) {
                float cn; float h2 = fin4b(Z, eb0, dcol, cB, cn); cmB = cn;
                st_coh(&HMT[(size_t)dcol * Bsz + srB + sown], h2);
            }
            arrive(&gsB[gm], ++epB);
        }
        // ---- A L1 ----
        {
            wait_all(gsA, epA);
            stageH9(XLA, HMT, srA, 0);
            __syncthreads();
            float4 A0 = Z4, A1 = Z4, A2 = Z4, A3 = Z4;
            consTvP<16>(P, W_WSUM, XLA + xo, A0, A1, A2, A3);
            float4 Z = redZ(A0, A1, A2, A3, khb, b3b);
            if (own) {
                float cn; float h2 = fin4b(Z, eb1, dcol, cmA, cn); cA = cn;
                st_coh(&HT[cur ^ 1][(size_t)dcol * Bsz + srA + sown], h2);
            }
            arrive(&gsA[gm], ++epA);
        }
        // ---- B L1 ----
        {
            wait_all(gsB, epB);
            stageH9(XLB, HMT, srB, 0);
            __syncthreads();
            float4 A0 = Z4, A1 = Z4, A2 = Z4, A3 = Z4;
            consTvP<16>(P, W_WSUM, XLB + xo, A0, A1, A2, A3);
            float4 Z = redZ(A0, A1, A2, A3, khb, b3b);
            if (own) {
                float cn; float h2 = fin4b(Z, eb1, dcol, cmB, cn); cB = cn;
                st_coh(&HT[cur ^ 1][(size_t)dcol * Bsz + srB + sown], h2);
            }
            arrive(&gsB[gm], ++epB);
        }
        cur ^= 1;
    }

    // ======================= decoder t=0 =======================
    {
        pref8(P, W_DU0);
        stageX9(XLA, dec_in, srA, 512);
        stageX9(XLB, dec_in, srB, 512);
        __syncthreads();
        // A L0 (c discarded)
        {
            float4 A0 = Z4, A1 = Z4, A2 = Z4, A3 = Z4;
            consTv<4>(W_DW0, XLA + 512 * NR + xo, A0, A1, A2, A3);
            wait_all(gsA, epA);
            stageH9(XLA, HT[cur], srA, 0);
            __syncthreads();
            consTvP<16>(P, W_DU0, XLA + xo, A0, A1, A2, A3);
            float4 Z = redZ(A0, A1, A2, A3, khb, b3b);
            if (own) {
                float cd; float h2 = fin4b(Z, db0, dcol, cA, cd);
                st_coh(&HMT[(size_t)dcol * Bsz + srA + sown], h2);
            }
            arrive(&gsA[gm], ++epA);
        }
        // B L0
        {
            float4 A0 = Z4, A1 = Z4, A2 = Z4, A3 = Z4;
            consTv<4>(W_DW0, XLB + 512 * NR + xo, A0, A1, A2, A3);
            wait_all(gsB, epB);
            stageH9(XLB, HT[cur], srB, 0);
            __syncthreads();
            consTvP<16>(P, W_DU0, XLB + xo, A0, A1, A2, A3);
            pref8(P, W_DU1);
            float4 Z = redZ(A0, A1, A2, A3, khb, b3b);
            if (own) {
                float cd; float h2 = fin4b(Z, db0, dcol, cB, cd);
                st_coh(&HMT[(size_t)dcol * Bsz + srB + sown], h2);
            }
            arrive(&gsB[gm], ++epB);
        }
        // A L1: h_old (rows 0..511) @ dU1 + hA (rows 512+) @ dW1; old carry
        {
            wait_all(gsA, epA);
            stageH9(XLA, HMT, srA, 512);
            __syncthreads();
            float4 A0 = Z4, A1 = Z4, A2 = Z4, A3 = Z4;
            consTvP<16>(P, W_DU1, XLA + xo, A0, A1, A2, A3);
            consTv<16>(W_DW1, XLA + 512 * NR + xo, A0, A1, A2, A3);
            float4 Z = redZ(A0, A1, A2, A3, khb, b3b);
            if (own) {
                float cn; float h2 = fin4b(Z, db1, dcol, cA, cn); cA = cn;
                st_coh(&HT[cur ^ 1][(size_t)dcol * Bsz + srA + sown], h2);
            }
            arrive(&gsA[gm], ++epA);
        }
        // B L1
        {
            wait_all(gsB, epB);
            stageH9(XLB, HMT, srB, 512);
            __syncthreads();
            float4 A0 = Z4, A1 = Z4, A2 = Z4, A3 = Z4;
            consTvP<16>(P, W_DU1, XLB + xo, A0, A1, A2, A3);
            consTv<16>(W_DW1, XLB + 512 * NR + xo, A0, A1, A2, A3);
            float4 Z = redZ(A0, A1, A2, A3, khb, b3b);
            if (own) {
                float cn; float h2 = fin4b(Z, db1, dcol, cB, cn); cB = cn;
                st_coh(&HT[cur ^ 1][(size_t)dcol * Bsz + srB + sown], h2);
            }
            arrive(&gsB[gm], ++epB);
        }
        cur ^= 1;
    }

    // ======================= decoder t=1..127 =======================
    for (int t = 1; t < Tsz; ++t) {
        const int tt = Tsz - t;
        pref8(P, W_WDECA);                     // chunk0 for A-L0 AND B-L0
        // ---- A L0 folded + fused out partials ----
        {
            wait_all(gsA, epA);
            stageH9(XLA, HT[cur], srA, 0);
            __syncthreads();
            float4 A0 = Z4, A1 = Z4, A2 = Z4, A3 = Z4;
            consTvP<16>(P, W_WDECA, XLA + xo, A0, A1, A2, A3);
            out_part9(XLA, DWL, OREDA, xo, koff, wv, khb, b3b, own, sown);
            float4 Z = redZ(A0, A1, A2, A3, khb, b3b);
            if (own) {
                float cd; float h2 = fin4b(Z, pBF, dcol, cA, cd);
                st_coh(&HMT[(size_t)dcol * Bsz + srA + sown], h2);
            }
            arrive(&gsA[gm], ++epA);
            if (tid < 32) {
                const int bb = tid >> 2, ff = tid & 3;
                const int fc = fcol0 + ff;
                const float* r = OREDA + bb * 16 + ff * 4;
                float s = r[0] + r[1] + r[2] + r[3] + db_[fc];
                out[((size_t)(srA + bb) * Tsz + tt) * Fsz + fc] = s;
            }
        }
        // ---- B L0 ----
        {
            wait_all(gsB, epB);
            stageH9(XLB, HT[cur], srB, 0);
            __syncthreads();
            float4 A0 = Z4, A1 = Z4, A2 = Z4, A3 = Z4;
            consTvP<16>(P, W_WDECA, XLB + xo, A0, A1, A2, A3);
            pref8(P, W_DU1);                   // chunk0 for A-L1 AND B-L1
            out_part9(XLB, DWL, OREDB, xo, koff, wv, khb, b3b, own, sown);
            float4 Z = redZ(A0, A1, A2, A3, khb, b3b);
            if (own) {
                float cd; float h2 = fin4b(Z, pBF, dcol, cB, cd);
                st_coh(&HMT[(size_t)dcol * Bsz + srB + sown], h2);
            }
            arrive(&gsB[gm], ++epB);
            if (tid < 32) {
                const int bb = tid >> 2, ff = tid & 3;
                const int fc = fcol0 + ff;
                const float* r = OREDB + bb * 16 + ff * 4;
                float s = r[0] + r[1] + r[2] + r[3] + db_[fc];
                out[((size_t)(srB + bb) * Tsz + tt) * Fsz + fc] = s;
            }
        }
        // ---- A L1 ----
        {
            wait_all(gsA, epA);
            stageH9(XLA, HMT, srA, 512);
            __syncthreads();
            float4 A0 = Z4, A1 = Z4, A2 = Z4, A3 = Z4;
            consTvP<16>(P, W_DU1, XLA + xo, A0, A1, A2, A3);
            consTv<16>(W_DW1, XLA + 512 * NR + xo, A0, A1, A2, A3);
            float4 Z = redZ(A0, A1, A2, A3, khb, b3b);
            if (own) {
                float cn; float h2 = fin4b(Z, db1, dcol, cA, cn); cA = cn;
                st_coh(&HT[cur ^ 1][(size_t)dcol * Bsz + srA + sown], h2);
            }
            arrive(&gsA[gm], ++epA);
        }
        // ---- B L1 ----
        {
            wait_all(gsB, epB);
            stageH9(XLB, HMT, srB, 512);
            __syncthreads();
            float4 A0 = Z4, A1 = Z4, A2 = Z4, A3 = Z4;
            consTvP<16>(P, W_DU1, XLB + xo, A0, A1, A2, A3);
            consTv<16>(W_DW1, XLB + 512 * NR + xo, A0, A1, A2, A3);
            float4 Z = redZ(A0, A1, A2, A3, khb, b3b);
            if (own) {
                float cn; float h2 = fin4b(Z, db1, dcol, cB, cn); cB = cn;
                st_coh(&HT[cur ^ 1][(size_t)dcol * Bsz + srB + sown], h2);
            }
            arrive(&gsB[gm], ++epB);
        }
        cur ^= 1;
    }

    // ======================= final out_127 -> row 0 =======================
    wait_all(gsA, epA);
    stageH9(XLA, HT[cur], srA, 0);
    __syncthreads();
    out_part9(XLA, DWL, OREDA, xo, koff, wv, khb, b3b, own, sown);
    wait_all(gsB, epB);
    stageH9(XLB, HT[cur], srB, 0);
    __syncthreads();
    out_part9(XLB, DWL, OREDB, xo, koff, wv, khb, b3b, own, sown);
    __syncthreads();
    if (tid < 64) {
        const int half = tid >> 5;
        const int l = tid & 31;
        const int bb = l >> 2, ff = l & 3;
        const int fc = fcol0 + ff;
        const float* ored = half ? OREDB : OREDA;
        const int sr = half ? srB : srA;
        const float* r = ored + bb * 16 + ff * 4;
        float s = r[0] + r[1] + r[2] + r[3] + db_[fc];
        out[((size_t)(sr + bb) * Tsz + 0) * Fsz + fc] = s;
    }
}

// =====================================================================
// ======================  v8 fallback kernel  =========================
// =====================================================================

__device__ __forceinline__ void stage_vec(float* XL, int xstr, int dstoff,
        const float* src, int row0, int ld, int klen, int c4shift) {
    const int q = klen >> 2;
    const int n4 = q * 16;
    for (int i = threadIdx.x; i < n4; i += NTHR) {
        const int row = i >> c4shift;
        const int c4 = i & (q - 1);
        float4 v = *(const float4*)(src + (size_t)(row0 + row) * ld + (c4 << 2));
        *(float4*)(XL + row * xstr + dstoff + (c4 << 2)) = v;
    }
}
__device__ __forceinline__ void stage_coh_T(float* XL, int xstr, int dstoff,
        const float* HTsrc, int row0) {
    for (int i = threadIdx.x; i < Dsz * 16; i += NTHR) {
        const int d = i >> 4;
        const int bb = i & 15;
        XL[bb * xstr + dstoff + d] = ld_coh(HTsrc + (size_t)d * Bsz + row0 + bb);
    }
}
__device__ __forceinline__ void acc_segS(float4& z, const float* xp,
                                         const float* W, int kbase, int ksub, int dcol) {
    for (int j = 0; j < ksub; ++j) {
        const float x = xp[j];
        const float* wr = W + (size_t)(kbase + j) * ND + dcol;
        z.x += x * wr[0];
        z.y += x * wr[Dsz];
        z.z += x * wr[2 * Dsz];
        z.w += x * wr[3 * Dsz];
    }
}
__device__ __forceinline__ void reduce4(float4& z) {
    z.x += __shfl_xor(z.x, 16); z.x += __shfl_xor(z.x, 32);
    z.y += __shfl_xor(z.y, 16); z.y += __shfl_xor(z.y, 32);
    z.z += __shfl_xor(z.z, 16); z.z += __shfl_xor(z.z, 32);
    z.w += __shfl_xor(z.w, 16); z.w += __shfl_xor(z.w, 32);
}
__device__ __forceinline__ float lstm_fin(float4 z, const float* bias, int dcol,
                                          float cprev, float& c2out) {
    float gi = sigf(z.x + bias[dcol]);
    float gf = sigf(z.y + bias[Dsz + dcol]);
    float gg = fmaxf(z.z + bias[2 * Dsz + dcol], 0.f);
    float go = sigf(z.w + bias[3 * Dsz + dcol]);
    float c2 = gf * cprev + gi * gg;
    c2out = c2;
    return go * fmaxf(c2, 0.f);
}
__device__ __forceinline__ void out_part(const float* XL, int xstr, float* ORED,
                                         int b, int kc, int w, int fcol,
                                         const float* dwT) {
    const int q = w >> 2;
    const float* xp = XL + b * xstr + q * 128 + kc * 32;
    const float* wt = dwT + (size_t)fcol * Dsz + q * 128 + kc * 32;
    float acc = 0.f;
    #pragma unroll
    for (int j = 0; j < 32; j += 4) {
        float4 x4 = *(const float4*)(xp + j);
        float4 w4 = *(const float4*)(wt + j);
        acc += x4.x * w4.x + x4.y * w4.y + x4.z * w4.z + x4.w * w4.w;
    }
    acc += __shfl_xor(acc, 16); acc += __shfl_xor(acc, 32);
    if ((threadIdx.x & 63) < 16) ORED[b * 16 + (w & 3) * 4 + q] = acc;
}

__global__ void __launch_bounds__(NTHR, 1)
lstm_ae_fb(const float* enc_in, const float* dec_in,
           const float* eW0, const float* eU0, const float* eb0,
           const float* eW1, const float* eU1, const float* eb1,
           const float* dW0, const float* dU0, const float* db0,
           const float* dW1, const float* dU1, const float* db1,
           const float* dw, const float* db_, float* out, float* ws)
{
    __shared__ float XL[16 * 1028];
    __shared__ float ORED[256];

    unsigned* fslots = (unsigned*)ws;
    float* HT[2] = { ws + OFF_HT0, ws + OFF_HT1 };
    float* HMT = ws + OFF_HMT;

    const int blkid = blockIdx.x;
    const int grp  = blkid & 7;
    const int mem  = blkid >> 3;
    const int sgrp = mem & 7;
    const int dslc = mem >> 3;
    const int gm   = dslc * 8 + grp;
    unsigned* gslots = (unsigned*)ws + 256 + sgrp * 64;

    const int tid  = threadIdx.x;
    const int w    = tid >> 6;
    const int lane = tid & 63;
    const int b    = lane & 15;
    const int kc   = lane >> 4;
    const int dcol = grp * 64 + dslc * 16 + w;
    const int bgl  = sgrp * 16 + b;
    const int row0 = sgrp * 16;
    const int fcol = grp * 16 + dslc * 4 + (w & 3);
    const int gid  = blkid * NTHR + tid;

    pack_wsum(ws + OFF_F_WSUM, eW1, eU1, gid);
    pack_wdeca_p(ws + OFF_F_WDECA, dU0, dW0, dw, gid);
    if (gid < ND) {
        float acc = db0[gid];
        for (int j = 0; j < Fsz; ++j) acc += db_[j] * dW0[(size_t)j * ND + gid];
        (ws + OFF_F_BF)[gid] = acc;
    }
    if (gid < Dsz * Fsz) {
        const int f = gid >> 9, k = gid & 511;
        (ws + OFF_F_DWT)[(size_t)f * Dsz + k] = dw[(size_t)k * Fsz + f];
    }
    const float* pWSUM = ws + OFF_F_WSUM;
    const float* pWDECA = ws + OFF_F_WDECA;
    const float* pBF = ws + OFF_F_BF;
    const float* pDWT = ws + OFF_F_DWT;
    gbar_all(fslots, blkid, 1);

    unsigned ep = 0;
    int cur = 0;
    float c_car = 0.f;

    for (int t = 0; t < Tsz; ++t) {
        stage_vec(XL, 644, 0, enc_in + (size_t)t * Fsz, row0, Tsz * Fsz, 128, 5);
        __syncthreads();
        float4 z = make_float4(0.f, 0.f, 0.f, 0.f);
        acc_segS(z, XL + b * 644 + kc * 32, eW0, kc * 32, 32, dcol);
        if (threadIdx.x < 64) {
            for (;;) {
                unsigned v = (threadIdx.x < 32)
                    ? __hip_atomic_load(&gslots[threadIdx.x], __ATOMIC_RELAXED,
                                        __HIP_MEMORY_SCOPE_AGENT)
                    : ep;
                if (__all(v >= ep)) break;
                __builtin_amdgcn_s_sleep(1);
            }
        }
        __syncthreads();
        stage_coh_T(XL, 644, 128, HT[cur], row0);
        __syncthreads();
        acc_segS(z, XL + b * 644 + 128 + kc * 128, eU0, kc * 128, 128, dcol);
        reduce4(z);
        float c1 = 0.f;
        if (lane < 16) {
            float h2 = lstm_fin(z, eb0, dcol, c_car, c1);
            st_coh(&HMT[(size_t)dcol * Bsz + bgl], h2);
        }
        arrive(&gslots[gm], ++ep);
        if (threadIdx.x < 64) {
            for (;;) {
                unsigned v = (threadIdx.x < 32)
                    ? __hip_atomic_load(&gslots[threadIdx.x], __ATOMIC_RELAXED,
                                        __HIP_MEMORY_SCOPE_AGENT)
                    : ep;
                if (__all(v >= ep)) break;
                __builtin_amdgcn_s_sleep(1);
            }
        }
        __syncthreads();
        stage_coh_T(XL, 516, 0, HMT, row0);
        __syncthreads();
        z = make_float4(0.f, 0.f, 0.f, 0.f);
        {
            const float4* wp = (const float4*)pWSUM + (size_t)dcol * 512 + kc * 128;
            const float* xp = XL + b * 516 + kc * 128;
            #pragma unroll 4
            for (int j = 0; j < 128; j += 4) {
                float4 x4 = *(const float4*)(xp + j);
                float4 w0 = wp[j], w1 = wp[j + 1], w2 = wp[j + 2], w3 = wp[j + 3];
                z.x += x4.x*w0.x + x4.y*w1.x + x4.z*w2.x + x4.w*w3.x;
                z.y += x4.x*w0.y + x4.y*w1.y + x4.z*w2.y + x4.w*w3.y;
                z.z += x4.x*w0.z + x4.y*w1.z + x4.z*w2.z + x4.w*w3.z;
                z.w += x4.x*w0.w + x4.y*w1.w + x4.z*w2.w + x4.w*w3.w;
            }
        }
        reduce4(z);
        if (lane < 16) {
            float c2;
            float h2 = lstm_fin(z, eb1, dcol, c1, c2);
            c_car = c2;
            st_coh(&HT[cur ^ 1][(size_t)dcol * Bsz + bgl], h2);
        }
        arrive(&gslots[gm], ++ep);
        cur ^= 1;
    }

    stage_vec(XL, 644, 0, dec_in, row0, Tsz * Fsz, 128, 5);
    __syncthreads();
    {
        float4 z = make_float4(0.f, 0.f, 0.f, 0.f);
        acc_segS(z, XL + b * 644 + kc * 32, dW0, kc * 32, 32, dcol);
        if (threadIdx.x < 64) {
            for (;;) {
                unsigned v = (threadIdx.x < 32)
                    ? __hip_atomic_load(&gslots[threadIdx.x], __ATOMIC_RELAXED,
                                        __HIP_MEMORY_SCOPE_AGENT)
                    : ep;
                if (__all(v >= ep)) break;
                __builtin_amdgcn_s_sleep(1);
            }
        }
        __syncthreads();
        stage_coh_T(XL, 644, 128, HT[cur], row0);
        __syncthreads();
        acc_segS(z, XL + b * 644 + 128 + kc * 128, dU0, kc * 128, 128, dcol);
        reduce4(z);
        if (lane < 16) {
            float cd;
            float h2 = lstm_fin(z, db0, dcol, c_car, cd);
            st_coh(&HMT[(size_t)dcol * Bsz + bgl], h2);
        }
        arrive(&gslots[gm], ++ep);
    }
    if (threadIdx.x < 64) {
        for (;;) {
            unsigned v = (threadIdx.x < 32)
                ? __hip_atomic_load(&gslots[threadIdx.x], __ATOMIC_RELAXED,
                                    __HIP_MEMORY_SCOPE_AGENT)
                : ep;
            if (__all(v >= ep)) break;
            __builtin_amdgcn_s_sleep(1);
        }
    }
    __syncthreads();
    stage_coh_T(XL, 1028, 0, HT[cur], row0);
    stage_coh_T(XL, 1028, 512, HMT, row0);
    __syncthreads();
    {
        float4 z = make_float4(0.f, 0.f, 0.f, 0.f);
        acc_segS(z, XL + b * 1028 + kc * 128, dU1, kc * 128, 128, dcol);
        acc_segS(z, XL + b * 1028 + 512 + kc * 128, dW1, kc * 128, 128, dcol);
        reduce4(z);
        if (lane < 16) {
            float c2;
            float h2 = lstm_fin(z, db1, dcol, c_car, c2);
            c_car = c2;
            st_coh(&HT[cur ^ 1][(size_t)dcol * Bsz + bgl], h2);
        }
    }
    arrive(&gslots[gm], ++ep);
    cur ^= 1;

    for (int t = 1; t < Tsz; ++t) {
        const int tt = Tsz - t;
        if (threadIdx.x < 64) {
            for (;;) {
                unsigned v = (threadIdx.x < 32)
                    ? __hip_atomic_load(&gslots[threadIdx.x], __ATOMIC_RELAXED,
                                        __HIP_MEMORY_SCOPE_AGENT)
                    : ep;
                if (__all(v >= ep)) break;
                __builtin_amdgcn_s_sleep(1);
            }
        }
        __syncthreads();
        stage_coh_T(XL, 1028, 0, HT[cur], row0);
        __syncthreads();
        {
            float4 z = make_float4(0.f, 0.f, 0.f, 0.f);
            const float4* wp = (const float4*)pWDECA + (size_t)dcol * 512 + kc * 128;
            const float* xp = XL + b * 1028 + kc * 128;
            #pragma unroll 4
            for (int j = 0; j < 128; j += 4) {
                float4 x4 = *(const float4*)(xp + j);
                float4 w0 = wp[j], w1 = wp[j + 1], w2 = wp[j + 2], w3 = wp[j + 3];
                z.x += x4.x*w0.x + x4.y*w1.x + x4.z*w2.x + x4.w*w3.x;
                z.y += x4.x*w0.y + x4.y*w1.y + x4.z*w2.y + x4.w*w3.y;
                z.z += x4.x*w0.z + x4.y*w1.z + x4.z*w2.z + x4.w*w3.z;
                z.w += x4.x*w0.w + x4.y*w1.w + x4.z*w2.w + x4.w*w3.w;
            }
            reduce4(z);
            out_part(XL, 1028, ORED, b, kc, w, fcol, pDWT);
            if (lane < 16) {
                float cd;
                float h2 = lstm_fin(z, pBF, dcol, c_car, cd);
                st_coh(&HMT[(size_t)dcol * Bsz + bgl], h2);
            }
        }
        arrive(&gslots[gm], ++ep);
        if (tid < 64) {
            const int bb = tid >> 2, ff = tid & 3;
            const int fc = grp * 16 + dslc * 4 + ff;
            const float* r = ORED + bb * 16 + ff * 4;
            float s = r[0] + r[1] + r[2] + r[3] + db_[fc];
            out[((size_t)(row0 + bb) * Tsz + tt) * Fsz + fc] = s;
        }
        if (threadIdx.x < 64) {
            for (;;) {
                unsigned v = (threadIdx.x < 32)
                    ? __hip_atomic_load(&gslots[threadIdx.x], __ATOMIC_RELAXED,
                                        __HIP_MEMORY_SCOPE_AGENT)
                    : ep;
                if (__all(v >= ep)) break;
                __builtin_amdgcn_s_sleep(1);
            }
        }
        __syncthreads();
        stage_coh_T(XL, 1028, 512, HMT, row0);
        __syncthreads();
        {
            float4 z = make_float4(0.f, 0.f, 0.f, 0.f);
            acc_segS(z, XL + b * 1028 + kc * 128, dU1, kc * 128, 128, dcol);
            acc_segS(z, XL + b * 1028 + 512 + kc * 128, dW1, kc * 128, 128, dcol);
            reduce4(z);
            if (lane < 16) {
                float c2;
                float h2 = lstm_fin(z, db1, dcol, c_car, c2);
                c_car = c2;
                st_coh(&HT[cur ^ 1][(size_t)dcol * Bsz + bgl], h2);
            }
        }
        arrive(&gslots[gm], ++ep);
        cur ^= 1;
    }

    if (threadIdx.x < 64) {
        for (;;) {
            unsigned v = (threadIdx.x < 32)
                ? __hip_atomic_load(&gslots[threadIdx.x], __ATOMIC_RELAXED,
                                    __HIP_MEMORY_SCOPE_AGENT)
                : ep;
            if (__all(v >= ep)) break;
            __builtin_amdgcn_s_sleep(1);
        }
    }
    __syncthreads();
    stage_coh_T(XL, 516, 0, HT[cur], row0);
    __syncthreads();
    out_part(XL, 516, ORED, b, kc, w, fcol, pDWT);
    __syncthreads();
    if (tid < 64) {
        const int bb = tid >> 2, ff = tid & 3;
        const int fc = grp * 16 + dslc * 4 + ff;
        const float* r = ORED + bb * 16 + ff * 4;
        float s = r[0] + r[1] + r[2] + r[3] + db_[fc];
        out[((size_t)(row0 + bb) * Tsz + 0) * Fsz + fc] = s;
    }
}

extern "C" void kernel_launch(void* const* d_in, const int* in_sizes, int n_in,
                              void* d_out, int out_size, void* d_ws, size_t ws_size,
                              hipStream_t stream) {
    (void)in_sizes; (void)n_in; (void)out_size;
    const float* enc_in = (const float*)d_in[0];
    const float* dec_in = (const float*)d_in[1];
    const float* eW0 = (const float*)d_in[2];
    const float* eU0 = (const float*)d_in[3];
    const float* eb0 = (const float*)d_in[4];
    const float* eW1 = (const float*)d_in[5];
    const float* eU1 = (const float*)d_in[6];
    const float* eb1 = (const float*)d_in[7];
    const float* dW0 = (const float*)d_in[8];
    const float* dU0 = (const float*)d_in[9];
    const float* db0 = (const float*)d_in[10];
    const float* dW1 = (const float*)d_in[11];
    const float* dU1 = (const float*)d_in[12];
    const float* db1 = (const float*)d_in[13];
    const float* dw  = (const float*)d_in[14];
    const float* db_ = (const float*)d_in[15];
    float* out = (float*)d_out;
    float* ws = (float*)d_ws;

    // zero: full-grid slots + 16x32 chain slots + HT0 (initial h = 0)
    hipMemsetAsync(d_ws, 0, (size_t)(OFF_HT0 + Dsz * Bsz) * sizeof(float), stream);

    if (ws_size >= (size_t)WS_PACKED_FLOATS * sizeof(float))
        lstm_ae_v11<<<NBLK, NTHR, 0, stream>>>(
            enc_in, dec_in, eW0, eU0, eb0, eW1, eU1, eb1,
            dW0, dU0, db0, dW1, dU1, db1, dw, db_, out, ws);
    else
        lstm_ae_fb<<<NBLK, NTHR, 0, stream>>>(
            enc_in, dec_in, eW0, eU0, eb0, eW1, eU1, eb1,
            dW0, dU0, db0, dW1, dU1, db1, dw, db_, out, ws);
}

// Round 7
// 19588.232 us; speedup vs baseline: 1.0199x; 1.0199x over previous
//
#include <hip/hip_runtime.h>

// =====================================================================
// LSTM autoencoder v12: v10 structure restored + chunk0 register
// prefetch (the only untested half of v11).
//
// v11 post-mortem (FETCH 0.9GB -> 27GB, dur 7.2 -> 20ms): agent-scope
// relaxed atomic POLL LOADS are serviced at the coherence point (HBM
// traffic on gfx950). Widening the poll from 1 wave/block to 16
// multiplied that traffic ~16-30x and saturated the fabric.
// RULE: keep spin-polling confined to one wave per block.
//
// v12 therefore uses v10's wait_grp (wave0-only poll + syncthreads)
// unchanged, and keeps only v11's benign half: weight chunk-0 register
// prefetch (8 x float4) issued before the wait, consumed by both
// chains' same-type phases. Everything else identical to v10.
// =====================================================================

#define Bsz 128
#define Tsz 128
#define Fsz 128
#define Dsz 512
#define ND  2048
#define NBLK 256
#define NTHR 1024

// ---- ws layout (float offsets) ----
#define OFF_HT0  1024
#define OFF_HT1  (OFF_HT0 + Dsz*Bsz)
#define OFF_HMT  (OFF_HT1 + Dsz*Bsz)
#define OFF_WEND (OFF_HMT + Dsz*Bsz)
// packed weights (gate-interleaved float4: Wp4[dcol*K + k] = {i,f,g,o})
#define OFF_P_EW0   OFF_WEND
#define OFF_P_EU0   (OFF_P_EW0 + Fsz*ND)
#define OFF_P_WSUM  (OFF_P_EU0 + Dsz*ND)
#define OFF_P_WDECA (OFF_P_WSUM + Dsz*ND)
#define OFF_P_DW0   (OFF_P_WDECA + Dsz*ND)
#define OFF_P_DU0   (OFF_P_DW0 + Fsz*ND)
#define OFF_P_DW1   (OFF_P_DU0 + Dsz*ND)
#define OFF_P_DU1   (OFF_P_DW1 + Dsz*ND)
#define OFF_P_BF    (OFF_P_DU1 + Dsz*ND)
#define OFF_P_DWT   (OFF_P_BF + ND)
#define WS_PACKED_FLOATS (OFF_P_DWT + Dsz*Fsz)
// fallback layout
#define OFF_F_WSUM  OFF_WEND
#define OFF_F_WDECA (OFF_F_WSUM + Dsz*ND)
#define OFF_F_BF    (OFF_F_WDECA + Dsz*ND)
#define OFF_F_DWT   (OFF_F_BF + ND)
#define WS_FALLBACK_FLOATS (OFF_F_DWT + Dsz*Fsz)

#define NR 12   // LDS row stride: 8 data + 4 pad floats (16B aligned)

__device__ __forceinline__ float sigf(float x) {
    return 1.0f / (1.0f + __expf(-x));
}
__device__ __forceinline__ float ld_coh(const float* p) {
    return __hip_atomic_load((float*)p, __ATOMIC_RELAXED, __HIP_MEMORY_SCOPE_AGENT);
}
__device__ __forceinline__ void st_coh(float* p, float v) {
    __hip_atomic_store(p, v, __ATOMIC_RELAXED, __HIP_MEMORY_SCOPE_AGENT);
}

// ---- split group barrier (32 members, per-chain slot arrays) ----
// POLL DISCIPLINE: only wave0 (threads <64) spins — agent-scope atomic
// poll loads are HBM traffic on gfx950 (v11 post-mortem).
__device__ __forceinline__ void arrive(unsigned* slot, unsigned ep) {
    __syncthreads();   // all waves' compute + coherent stores drained
    if (threadIdx.x == 0)
        __hip_atomic_store(slot, ep, __ATOMIC_RELEASE, __HIP_MEMORY_SCOPE_AGENT);
}
__device__ __forceinline__ void wait_grp(unsigned* gslots, unsigned ep) {
    if (threadIdx.x < 64) {
        for (;;) {
            unsigned v = (threadIdx.x < 32)
                ? __hip_atomic_load(&gslots[threadIdx.x], __ATOMIC_RELAXED,
                                    __HIP_MEMORY_SCOPE_AGENT)
                : ep;
            if (__all(v >= ep)) break;
            __builtin_amdgcn_s_sleep(1);
        }
    }
    __syncthreads();
}
__device__ __forceinline__ void gbar_all(unsigned* slots, int blkid, unsigned ep) {
    __syncthreads();
    if (threadIdx.x == 0) {
        __threadfence();
        __hip_atomic_store(&slots[blkid], ep, __ATOMIC_RELEASE,
                           __HIP_MEMORY_SCOPE_AGENT);
    }
    if (threadIdx.x < 64) {
        for (;;) {
            unsigned mn = ~0u;
            #pragma unroll
            for (int q = 0; q < 4; ++q) {
                unsigned v = __hip_atomic_load(&slots[threadIdx.x * 4 + q],
                                               __ATOMIC_RELAXED, __HIP_MEMORY_SCOPE_AGENT);
                mn = min(mn, v);
            }
            if (__all(mn >= ep)) break;
            __builtin_amdgcn_s_sleep(1);
        }
        if (threadIdx.x == 0) __threadfence();
    }
    __syncthreads();
}

// ---- P0 packing (identical to v6..v10) ----
__device__ void pack_gate(float* dst, const float* src, int K, int kshift, int gid) {
    const int total = K * Dsz;
    for (int u = gid; u < total; u += NBLK * NTHR) {
        const int dd = u >> kshift;
        const int k = u & (K - 1);
        const float* sp = src + (size_t)k * ND + dd;
        ((float4*)dst)[u] = make_float4(sp[0], sp[Dsz], sp[2 * Dsz], sp[3 * Dsz]);
    }
}
__device__ void pack_wsum(float* dst, const float* a, const float* bsrc, int gid) {
    for (int u = gid; u < Dsz * Dsz; u += NBLK * NTHR) {
        const int dd = u >> 9, k = u & 511;
        const float* pa = a + (size_t)k * ND + dd;
        const float* pb = bsrc + (size_t)k * ND + dd;
        ((float4*)dst)[u] = make_float4(pa[0] + pb[0], pa[Dsz] + pb[Dsz],
                                        pa[2*Dsz] + pb[2*Dsz], pa[3*Dsz] + pb[3*Dsz]);
    }
}
__device__ void pack_wdeca_p(float* dst, const float* dU0, const float* dW0,
                             const float* dw, int gid) {
    for (int u = gid; u < Dsz * Dsz; u += NBLK * NTHR) {
        const int dd = u >> 9, k = u & 511;
        const float* pu = dU0 + (size_t)k * ND + dd;
        float a0 = pu[0], a1 = pu[Dsz], a2 = pu[2*Dsz], a3 = pu[3*Dsz];
        const float* dwr = dw + k * Fsz;
        for (int j = 0; j < Fsz; ++j) {
            const float wv = dwr[j];
            const float* dr = dW0 + (size_t)j * ND + dd;
            a0 += wv * dr[0]; a1 += wv * dr[Dsz];
            a2 += wv * dr[2*Dsz]; a3 += wv * dr[3*Dsz];
        }
        ((float4*)dst)[u] = make_float4(a0, a1, a2, a3);
    }
}

// =====================================================================
// ======================  v12 kernel  =================================
// =====================================================================

// stage 512 h rows (8 samples) from transposed coherent buffer
__device__ __forceinline__ void stageH9(float* XL, const float* HTsrc, int sr, int rbase) {
    #pragma unroll
    for (int ii = 0; ii < 4; ++ii) {
        const int i = (int)threadIdx.x + ii * NTHR;
        const int r = i >> 3, bb = i & 7;
        XL[(rbase + r) * NR + bb] = ld_coh(HTsrc + (size_t)r * Bsz + sr + bb);
    }
}
// stage 128 x rows (8 samples), 1 elem/thread
__device__ __forceinline__ void stageX9(float* XL, const float* src, int sr, int rbase) {
    const int r = (int)threadIdx.x & 127, bb = (int)threadIdx.x >> 7;
    XL[(rbase + r) * NR + bb] = src[(size_t)(sr + bb) * (Tsz * Fsz) + r];
}

#define FMA16(A0,A1,A2,A3,x4,w4) \
    A0.x += x4.x*w4.x; A0.y += x4.x*w4.y; A0.z += x4.x*w4.z; A0.w += x4.x*w4.w; \
    A1.x += x4.y*w4.x; A1.y += x4.y*w4.y; A1.z += x4.y*w4.z; A1.w += x4.y*w4.w; \
    A2.x += x4.z*w4.x; A2.y += x4.z*w4.y; A2.z += x4.z*w4.z; A2.w += x4.z*w4.w; \
    A3.x += x4.w*w4.x; A3.y += x4.w*w4.y; A3.z += x4.w*w4.z; A3.w += x4.w*w4.w;

// prefetch first 8 weight rows (chunk0) into registers
__device__ __forceinline__ void pref8(float4 P[8], const float4* __restrict__ Wp) {
    #pragma unroll
    for (int j = 0; j < 8; ++j) P[j] = Wp[j * 32];
}

// consume NJ*32 K-rows; plain (streamed weights)
template<int NJ>
__device__ __forceinline__ void consTv(const float4* __restrict__ Wp,
        const float* __restrict__ Xb,
        float4& A0, float4& A1, float4& A2, float4& A3)
{
    #pragma unroll 8
    for (int j = 0; j < NJ; ++j) {
        const float4 x4 = *(const float4*)(Xb + j * (32 * NR));
        const float4 w4 = Wp[j * 32];
        FMA16(A0, A1, A2, A3, x4, w4)
    }
}
// consume with register-prefetched chunk0 (j<8 from P)
template<int NJ>
__device__ __forceinline__ void consTvP(const float4 P[8],
        const float4* __restrict__ Wp, const float* __restrict__ Xb,
        float4& A0, float4& A1, float4& A2, float4& A3)
{
    #pragma unroll
    for (int j = 0; j < NJ; ++j) {
        const float4 x4 = *(const float4*)(Xb + j * (32 * NR));
        const float4 w4 = (j < 8) ? P[j] : Wp[j * 32];
        FMA16(A0, A1, A2, A3, x4, w4)
    }
}

// ---- cheap cross-lane reduction (identical to v10) ----
__device__ __forceinline__ float dppx1(float v) {   // xor 1
    return v + __int_as_float(__builtin_amdgcn_mov_dpp(
        __float_as_int(v), 0xB1, 0xf, 0xf, true));
}
__device__ __forceinline__ float dppx2(float v) {   // xor 2
    return v + __int_as_float(__builtin_amdgcn_mov_dpp(
        __float_as_int(v), 0x4E, 0xf, 0xf, true));
}
__device__ __forceinline__ float dpphm(float v) {   // i^7 within 8
    return v + __int_as_float(__builtin_amdgcn_mov_dpp(
        __float_as_int(v), 0x141, 0xf, 0xf, true));
}
#define HXCH(lo, hi, mask, cond) { \
    float s_ = (cond) ? (lo) : (hi); \
    float r_ = __shfl_xor(s_, mask); \
    if (cond) (hi) += r_; else (lo) += r_; }

__device__ __forceinline__ float4 redZ(float4 A0, float4 A1, float4 A2, float4 A3,
                                       bool khb, bool b3b)
{
    HXCH(A0.x, A2.x, 32, khb) HXCH(A0.y, A2.y, 32, khb)
    HXCH(A0.z, A2.z, 32, khb) HXCH(A0.w, A2.w, 32, khb)
    HXCH(A1.x, A3.x, 32, khb) HXCH(A1.y, A3.y, 32, khb)
    HXCH(A1.z, A3.z, 32, khb) HXCH(A1.w, A3.w, 32, khb)
    float4 B0, B1;
    B0.x = khb ? A2.x : A0.x; B0.y = khb ? A2.y : A0.y;
    B0.z = khb ? A2.z : A0.z; B0.w = khb ? A2.w : A0.w;
    B1.x = khb ? A3.x : A1.x; B1.y = khb ? A3.y : A1.y;
    B1.z = khb ? A3.z : A1.z; B1.w = khb ? A3.w : A1.w;
    HXCH(B0.x, B1.x, 8, b3b) HXCH(B0.y, B1.y, 8, b3b)
    HXCH(B0.z, B1.z, 8, b3b) HXCH(B0.w, B1.w, 8, b3b)
    float4 Z;
    Z.x = b3b ? B1.x : B0.x; Z.y = b3b ? B1.y : B0.y;
    Z.z = b3b ? B1.z : B0.z; Z.w = b3b ? B1.w : B0.w;
    Z.x = dppx1(Z.x); Z.y = dppx1(Z.y); Z.z = dppx1(Z.z); Z.w = dppx1(Z.w);
    Z.x = dppx2(Z.x); Z.y = dppx2(Z.y); Z.z = dppx2(Z.z); Z.w = dppx2(Z.w);
    Z.x = dpphm(Z.x); Z.y = dpphm(Z.y); Z.z = dpphm(Z.z); Z.w = dpphm(Z.w);
    return Z;
}

__device__ __forceinline__ float fin4b(float4 z, const float* bias, int dcol,
                                       float cprev, float& c2o) {
    float gi = sigf(z.x + bias[dcol]);
    float gf = sigf(z.y + bias[Dsz + dcol]);
    float gg = fmaxf(z.z + bias[2 * Dsz + dcol], 0.f);
    float go = sigf(z.w + bias[3 * Dsz + dcol]);
    float c2 = gf * cprev + gi * gg;
    c2o = c2;
    return go * fmaxf(c2, 0.f);
}

// fused dense-row partials for one chain: ORED[sample][ff*4+qk]
__device__ __forceinline__ void out_part9(const float* XL, const float* DWL, float* ORED,
                                          int xo, int koff, int wv,
                                          bool khb, bool b3b, bool own, int sown)
{
    const int ff = wv & 3, qk = wv >> 2;
    float o0 = 0.f, o1 = 0.f, o2 = 0.f, o3 = 0.f;
    const float* Xb = XL + qk * 128 * NR + xo;
    const float* Wb = DWL + ff * 512 + qk * 128 + koff;
    #pragma unroll
    for (int j = 0; j < 4; ++j) {
        const float4 x4 = *(const float4*)(Xb + j * (32 * NR));
        const float w = Wb[j * 32];
        o0 += x4.x * w; o1 += x4.y * w; o2 += x4.z * w; o3 += x4.w * w;
    }
    HXCH(o0, o2, 32, khb) HXCH(o1, o3, 32, khb)
    float p0 = khb ? o2 : o0;
    float p1 = khb ? o3 : o1;
    HXCH(p0, p1, 8, b3b)
    float o = b3b ? p1 : p0;
    o = dppx1(o); o = dppx2(o); o = dpphm(o);
    if (own) ORED[sown * 16 + ff * 4 + qk] = o;
}

__global__ void __launch_bounds__(NTHR, 1)
lstm_ae_v12(const float* enc_in, const float* dec_in,
            const float* eW0, const float* eU0, const float* eb0,
            const float* eW1, const float* eU1, const float* eb1,
            const float* dW0, const float* dU0, const float* db0,
            const float* dW1, const float* dU1, const float* db1,
            const float* dw, const float* db_, float* out, float* ws)
{
    __shared__ float XLA[1024 * NR];   // 48 KB chain A
    __shared__ float XLB[1024 * NR];   // 48 KB chain B
    __shared__ float DWL[4 * 512];     //  8 KB resident dwT slice (4 fcols)
    __shared__ float OREDA[128];
    __shared__ float OREDB[128];

    unsigned* fslots = (unsigned*)ws;
    float* HT[2] = { ws + OFF_HT0, ws + OFF_HT1 };
    float* HMT = ws + OFF_HMT;

    const int blkid = blockIdx.x;
    const int grp  = blkid & 7;
    const int mem  = blkid >> 3;
    const int sgrp = mem & 7;
    const int dslc = mem >> 3;
    const int gm   = dslc * 8 + grp;
    const int chA  = sgrp * 2, chB = chA + 1;
    unsigned* gsA = (unsigned*)ws + 256 + chA * 32;
    unsigned* gsB = (unsigned*)ws + 256 + chB * 32;
    const int srA = sgrp * 16;
    const int srB = sgrp * 16 + 8;

    const int tid  = threadIdx.x;
    const int wv   = tid >> 6;
    const int lane = tid & 63;
    const int kh   = lane >> 5;
    const int qb2  = (lane >> 4) & 1;
    const int kc   = lane & 15;
    const int koff = kh * 16 + kc;
    const int dcol = grp * 64 + dslc * 16 + wv;
    const int fcol0 = grp * 16 + dslc * 4;
    const int gid  = blkid * NTHR + tid;
    const bool khb = (kh != 0);
    const bool b3b = ((kc & 8) != 0);
    const bool own = ((kc & 7) == 0);
    const int sown = qb2 * 4 + kh * 2 + ((kc >> 3) & 1);
    const int xo   = koff * NR + qb2 * 4;

    // ---- P0 ----
    pack_gate(ws + OFF_P_EW0, eW0, Fsz, 7, gid);
    pack_gate(ws + OFF_P_EU0, eU0, Dsz, 9, gid);
    pack_wsum(ws + OFF_P_WSUM, eW1, eU1, gid);
    pack_wdeca_p(ws + OFF_P_WDECA, dU0, dW0, dw, gid);
    pack_gate(ws + OFF_P_DW0, dW0, Fsz, 7, gid);
    pack_gate(ws + OFF_P_DU0, dU0, Dsz, 9, gid);
    pack_gate(ws + OFF_P_DW1, dW1, Dsz, 9, gid);
    pack_gate(ws + OFF_P_DU1, dU1, Dsz, 9, gid);
    if (gid < ND) {
        float acc = db0[gid];
        for (int j = 0; j < Fsz; ++j) acc += db_[j] * dW0[(size_t)j * ND + gid];
        (ws + OFF_P_BF)[gid] = acc;
    }
    if (gid < Dsz * Fsz) {
        const int f = gid >> 9, k = gid & 511;
        (ws + OFF_P_DWT)[(size_t)f * Dsz + k] = dw[(size_t)k * Fsz + f];
    }
    gbar_all(fslots, blkid, 1);

    // resident dwT slice
    #pragma unroll
    for (int ii = 0; ii < 2; ++ii) {
        const int i = tid + ii * NTHR;
        DWL[i] = (ws + OFF_P_DWT)[(size_t)(fcol0 + (i >> 9)) * Dsz + (i & 511)];
    }
    __syncthreads();

    const float* pBF = ws + OFF_P_BF;
    const float4* W_EW0   = (const float4*)(ws + OFF_P_EW0)   + (size_t)dcol * 128 + koff;
    const float4* W_EU0   = (const float4*)(ws + OFF_P_EU0)   + (size_t)dcol * 512 + koff;
    const float4* W_WSUM  = (const float4*)(ws + OFF_P_WSUM)  + (size_t)dcol * 512 + koff;
    const float4* W_WDECA = (const float4*)(ws + OFF_P_WDECA) + (size_t)dcol * 512 + koff;
    const float4* W_DW0   = (const float4*)(ws + OFF_P_DW0)   + (size_t)dcol * 128 + koff;
    const float4* W_DU0   = (const float4*)(ws + OFF_P_DU0)   + (size_t)dcol * 512 + koff;
    const float4* W_DW1   = (const float4*)(ws + OFF_P_DW1)   + (size_t)dcol * 512 + koff;
    const float4* W_DU1   = (const float4*)(ws + OFF_P_DU1)   + (size_t)dcol * 512 + koff;

    unsigned epA = 0, epB = 0;
    int cur = 0;
    float cA = 0.f, cmA = 0.f, cB = 0.f, cmB = 0.f;
    const float4 Z4 = make_float4(0.f, 0.f, 0.f, 0.f);
    float4 P[8];

    // ======================= encoder =======================
    for (int t = 0; t < Tsz; ++t) {
        pref8(P, W_EU0);                       // chunk0 for A-L0 AND B-L0
        stageX9(XLA, enc_in + (size_t)t * Fsz, srA, 512);
        stageX9(XLB, enc_in + (size_t)t * Fsz, srB, 512);
        __syncthreads();
        // ---- A L0 ----
        {
            float4 A0 = Z4, A1 = Z4, A2 = Z4, A3 = Z4;
            consTv<4>(W_EW0, XLA + 512 * NR + xo, A0, A1, A2, A3);
            wait_grp(gsA, epA);
            stageH9(XLA, HT[cur], srA, 0);
            __syncthreads();
            consTvP<16>(P, W_EU0, XLA + xo, A0, A1, A2, A3);
            float4 Z = redZ(A0, A1, A2, A3, khb, b3b);
            if (own) {
                float cn; float h2 = fin4b(Z, eb0, dcol, cA, cn); cmA = cn;
                st_coh(&HMT[(size_t)dcol * Bsz + srA + sown], h2);
            }
            arrive(&gsA[gm], ++epA);
        }
        // ---- B L0 ----
        {
            float4 A0 = Z4, A1 = Z4, A2 = Z4, A3 = Z4;
            consTv<4>(W_EW0, XLB + 512 * NR + xo, A0, A1, A2, A3);
            wait_grp(gsB, epB);
            stageH9(XLB, HT[cur], srB, 0);
            __syncthreads();
            consTvP<16>(P, W_EU0, XLB + xo, A0, A1, A2, A3);
            pref8(P, W_WSUM);                  // chunk0 for A-L1 AND B-L1
            float4 Z = redZ(A0, A1, A2, A3, khb, b3b);
            if (own) {
                float cn; float h2 = fin4b(Z, eb0, dcol, cB, cn); cmB = cn;
                st_coh(&HMT[(size_t)dcol * Bsz + srB + sown], h2);
            }
            arrive(&gsB[gm], ++epB);
        }
        // ---- A L1 ----
        {
            wait_grp(gsA, epA);
            stageH9(XLA, HMT, srA, 0);
            __syncthreads();
            float4 A0 = Z4, A1 = Z4, A2 = Z4, A3 = Z4;
            consTvP<16>(P, W_WSUM, XLA + xo, A0, A1, A2, A3);
            float4 Z = redZ(A0, A1, A2, A3, khb, b3b);
            if (own) {
                float cn; float h2 = fin4b(Z, eb1, dcol, cmA, cn); cA = cn;
                st_coh(&HT[cur ^ 1][(size_t)dcol * Bsz + srA + sown], h2);
            }
            arrive(&gsA[gm], ++epA);
        }
        // ---- B L1 ----
        {
            wait_grp(gsB, epB);
            stageH9(XLB, HMT, srB, 0);
            __syncthreads();
            float4 A0 = Z4, A1 = Z4, A2 = Z4, A3 = Z4;
            consTvP<16>(P, W_WSUM, XLB + xo, A0, A1, A2, A3);
            float4 Z = redZ(A0, A1, A2, A3, khb, b3b);
            if (own) {
                float cn; float h2 = fin4b(Z, eb1, dcol, cmB, cn); cB = cn;
                st_coh(&HT[cur ^ 1][(size_t)dcol * Bsz + srB + sown], h2);
            }
            arrive(&gsB[gm], ++epB);
        }
        cur ^= 1;
    }

    // ======================= decoder t=0 =======================
    {
        pref8(P, W_DU0);
        stageX9(XLA, dec_in, srA, 512);
        stageX9(XLB, dec_in, srB, 512);
        __syncthreads();
        // A L0 (c discarded)
        {
            float4 A0 = Z4, A1 = Z4, A2 = Z4, A3 = Z4;
            consTv<4>(W_DW0, XLA + 512 * NR + xo, A0, A1, A2, A3);
            wait_grp(gsA, epA);
            stageH9(XLA, HT[cur], srA, 0);
            __syncthreads();
            consTvP<16>(P, W_DU0, XLA + xo, A0, A1, A2, A3);
            float4 Z = redZ(A0, A1, A2, A3, khb, b3b);
            if (own) {
                float cd; float h2 = fin4b(Z, db0, dcol, cA, cd);
                st_coh(&HMT[(size_t)dcol * Bsz + srA + sown], h2);
            }
            arrive(&gsA[gm], ++epA);
        }
        // B L0
        {
            float4 A0 = Z4, A1 = Z4, A2 = Z4, A3 = Z4;
            consTv<4>(W_DW0, XLB + 512 * NR + xo, A0, A1, A2, A3);
            wait_grp(gsB, epB);
            stageH9(XLB, HT[cur], srB, 0);
            __syncthreads();
            consTvP<16>(P, W_DU0, XLB + xo, A0, A1, A2, A3);
            pref8(P, W_DU1);
            float4 Z = redZ(A0, A1, A2, A3, khb, b3b);
            if (own) {
                float cd; float h2 = fin4b(Z, db0, dcol, cB, cd);
                st_coh(&HMT[(size_t)dcol * Bsz + srB + sown], h2);
            }
            arrive(&gsB[gm], ++epB);
        }
        // A L1: h_old (rows 0..511) @ dU1 + hA (rows 512+) @ dW1; old carry
        {
            wait_grp(gsA, epA);
            stageH9(XLA, HMT, srA, 512);
            __syncthreads();
            float4 A0 = Z4, A1 = Z4, A2 = Z4, A3 = Z4;
            consTvP<16>(P, W_DU1, XLA + xo, A0, A1, A2, A3);
            consTv<16>(W_DW1, XLA + 512 * NR + xo, A0, A1, A2, A3);
            float4 Z = redZ(A0, A1, A2, A3, khb, b3b);
            if (own) {
                float cn; float h2 = fin4b(Z, db1, dcol, cA, cn); cA = cn;
                st_coh(&HT[cur ^ 1][(size_t)dcol * Bsz + srA + sown], h2);
            }
            arrive(&gsA[gm], ++epA);
        }
        // B L1
        {
            wait_grp(gsB, epB);
            stageH9(XLB, HMT, srB, 512);
            __syncthreads();
            float4 A0 = Z4, A1 = Z4, A2 = Z4, A3 = Z4;
            consTvP<16>(P, W_DU1, XLB + xo, A0, A1, A2, A3);
            consTv<16>(W_DW1, XLB + 512 * NR + xo, A0, A1, A2, A3);
            float4 Z = redZ(A0, A1, A2, A3, khb, b3b);
            if (own) {
                float cn; float h2 = fin4b(Z, db1, dcol, cB, cn); cB = cn;
                st_coh(&HT[cur ^ 1][(size_t)dcol * Bsz + srB + sown], h2);
            }
            arrive(&gsB[gm], ++epB);
        }
        cur ^= 1;
    }

    // ======================= decoder t=1..127 =======================
    for (int t = 1; t < Tsz; ++t) {
        const int tt = Tsz - t;
        pref8(P, W_WDECA);                     // chunk0 for A-L0 AND B-L0
        // ---- A L0 folded + fused out partials ----
        {
            wait_grp(gsA, epA);
            stageH9(XLA, HT[cur], srA, 0);
            __syncthreads();
            float4 A0 = Z4, A1 = Z4, A2 = Z4, A3 = Z4;
            consTvP<16>(P, W_WDECA, XLA + xo, A0, A1, A2, A3);
            out_part9(XLA, DWL, OREDA, xo, koff, wv, khb, b3b, own, sown);
            float4 Z = redZ(A0, A1, A2, A3, khb, b3b);
            if (own) {
                float cd; float h2 = fin4b(Z, pBF, dcol, cA, cd);
                st_coh(&HMT[(size_t)dcol * Bsz + srA + sown], h2);
            }
            arrive(&gsA[gm], ++epA);
            if (tid < 32) {
                const int bb = tid >> 2, ff = tid & 3;
                const int fc = fcol0 + ff;
                const float* r = OREDA + bb * 16 + ff * 4;
                float s = r[0] + r[1] + r[2] + r[3] + db_[fc];
                out[((size_t)(srA + bb) * Tsz + tt) * Fsz + fc] = s;
            }
        }
        // ---- B L0 ----
        {
            wait_grp(gsB, epB);
            stageH9(XLB, HT[cur], srB, 0);
            __syncthreads();
            float4 A0 = Z4, A1 = Z4, A2 = Z4, A3 = Z4;
            consTvP<16>(P, W_WDECA, XLB + xo, A0, A1, A2, A3);
            pref8(P, W_DU1);                   // chunk0 for A-L1 AND B-L1
            out_part9(XLB, DWL, OREDB, xo, koff, wv, khb, b3b, own, sown);
            float4 Z = redZ(A0, A1, A2, A3, khb, b3b);
            if (own) {
                float cd; float h2 = fin4b(Z, pBF, dcol, cB, cd);
                st_coh(&HMT[(size_t)dcol * Bsz + srB + sown], h2);
            }
            arrive(&gsB[gm], ++epB);
            if (tid < 32) {
                const int bb = tid >> 2, ff = tid & 3;
                const int fc = fcol0 + ff;
                const float* r = OREDB + bb * 16 + ff * 4;
                float s = r[0] + r[1] + r[2] + r[3] + db_[fc];
                out[((size_t)(srB + bb) * Tsz + tt) * Fsz + fc] = s;
            }
        }
        // ---- A L1 ----
        {
            wait_grp(gsA, epA);
            stageH9(XLA, HMT, srA, 512);
            __syncthreads();
            float4 A0 = Z4, A1 = Z4, A2 = Z4, A3 = Z4;
            consTvP<16>(P, W_DU1, XLA + xo, A0, A1, A2, A3);
            consTv<16>(W_DW1, XLA + 512 * NR + xo, A0, A1, A2, A3);
            float4 Z = redZ(A0, A1, A2, A3, khb, b3b);
            if (own) {
                float cn; float h2 = fin4b(Z, db1, dcol, cA, cn); cA = cn;
                st_coh(&HT[cur ^ 1][(size_t)dcol * Bsz + srA + sown], h2);
            }
            arrive(&gsA[gm], ++epA);
        }
        // ---- B L1 ----
        {
            wait_grp(gsB, epB);
            stageH9(XLB, HMT, srB, 512);
            __syncthreads();
            float4 A0 = Z4, A1 = Z4, A2 = Z4, A3 = Z4;
            consTvP<16>(P, W_DU1, XLB + xo, A0, A1, A2, A3);
            consTv<16>(W_DW1, XLB + 512 * NR + xo, A0, A1, A2, A3);
            float4 Z = redZ(A0, A1, A2, A3, khb, b3b);
            if (own) {
                float cn; float h2 = fin4b(Z, db1, dcol, cB, cn); cB = cn;
                st_coh(&HT[cur ^ 1][(size_t)dcol * Bsz + srB + sown], h2);
            }
            arrive(&gsB[gm], ++epB);
        }
        cur ^= 1;
    }

    // ======================= final out_127 -> row 0 =======================
    wait_grp(gsA, epA);
    stageH9(XLA, HT[cur], srA, 0);
    __syncthreads();
    out_part9(XLA, DWL, OREDA, xo, koff, wv, khb, b3b, own, sown);
    wait_grp(gsB, epB);
    stageH9(XLB, HT[cur], srB, 0);
    __syncthreads();
    out_part9(XLB, DWL, OREDB, xo, koff, wv, khb, b3b, own, sown);
    __syncthreads();
    if (tid < 64) {
        const int half = tid >> 5;
        const int l = tid & 31;
        const int bb = l >> 2, ff = l & 3;
        const int fc = fcol0 + ff;
        const float* ored = half ? OREDB : OREDA;
        const int sr = half ? srB : srA;
        const float* r = ored + bb * 16 + ff * 4;
        float s = r[0] + r[1] + r[2] + r[3] + db_[fc];
        out[((size_t)(sr + bb) * Tsz + 0) * Fsz + fc] = s;
    }
}

// =====================================================================
// ======================  v8 fallback kernel  =========================
// =====================================================================

__device__ __forceinline__ void stage_vec(float* XL, int xstr, int dstoff,
        const float* src, int row0, int ld, int klen, int c4shift) {
    const int q = klen >> 2;
    const int n4 = q * 16;
    for (int i = threadIdx.x; i < n4; i += NTHR) {
        const int row = i >> c4shift;
        const int c4 = i & (q - 1);
        float4 v = *(const float4*)(src + (size_t)(row0 + row) * ld + (c4 << 2));
        *(float4*)(XL + row * xstr + dstoff + (c4 << 2)) = v;
    }
}
__device__ __forceinline__ void stage_coh_T(float* XL, int xstr, int dstoff,
        const float* HTsrc, int row0) {
    for (int i = threadIdx.x; i < Dsz * 16; i += NTHR) {
        const int d = i >> 4;
        const int bb = i & 15;
        XL[bb * xstr + dstoff + d] = ld_coh(HTsrc + (size_t)d * Bsz + row0 + bb);
    }
}
__device__ __forceinline__ void acc_segS(float4& z, const float* xp,
                                         const float* W, int kbase, int ksub, int dcol) {
    for (int j = 0; j < ksub; ++j) {
        const float x = xp[j];
        const float* wr = W + (size_t)(kbase + j) * ND + dcol;
        z.x += x * wr[0];
        z.y += x * wr[Dsz];
        z.z += x * wr[2 * Dsz];
        z.w += x * wr[3 * Dsz];
    }
}
__device__ __forceinline__ void reduce4(float4& z) {
    z.x += __shfl_xor(z.x, 16); z.x += __shfl_xor(z.x, 32);
    z.y += __shfl_xor(z.y, 16); z.y += __shfl_xor(z.y, 32);
    z.z += __shfl_xor(z.z, 16); z.z += __shfl_xor(z.z, 32);
    z.w += __shfl_xor(z.w, 16); z.w += __shfl_xor(z.w, 32);
}
__device__ __forceinline__ float lstm_fin(float4 z, const float* bias, int dcol,
                                          float cprev, float& c2out) {
    float gi = sigf(z.x + bias[dcol]);
    float gf = sigf(z.y + bias[Dsz + dcol]);
    float gg = fmaxf(z.z + bias[2 * Dsz + dcol], 0.f);
    float go = sigf(z.w + bias[3 * Dsz + dcol]);
    float c2 = gf * cprev + gi * gg;
    c2out = c2;
    return go * fmaxf(c2, 0.f);
}
__device__ __forceinline__ void out_part(const float* XL, int xstr, float* ORED,
                                         int b, int kc, int w, int fcol,
                                         const float* dwT) {
    const int q = w >> 2;
    const float* xp = XL + b * xstr + q * 128 + kc * 32;
    const float* wt = dwT + (size_t)fcol * Dsz + q * 128 + kc * 32;
    float acc = 0.f;
    #pragma unroll
    for (int j = 0; j < 32; j += 4) {
        float4 x4 = *(const float4*)(xp + j);
        float4 w4 = *(const float4*)(wt + j);
        acc += x4.x * w4.x + x4.y * w4.y + x4.z * w4.z + x4.w * w4.w;
    }
    acc += __shfl_xor(acc, 16); acc += __shfl_xor(acc, 32);
    if ((threadIdx.x & 63) < 16) ORED[b * 16 + (w & 3) * 4 + q] = acc;
}

__global__ void __launch_bounds__(NTHR, 1)
lstm_ae_fb(const float* enc_in, const float* dec_in,
           const float* eW0, const float* eU0, const float* eb0,
           const float* eW1, const float* eU1, const float* eb1,
           const float* dW0, const float* dU0, const float* db0,
           const float* dW1, const float* dU1, const float* db1,
           const float* dw, const float* db_, float* out, float* ws)
{
    __shared__ float XL[16 * 1028];
    __shared__ float ORED[256];

    unsigned* fslots = (unsigned*)ws;
    float* HT[2] = { ws + OFF_HT0, ws + OFF_HT1 };
    float* HMT = ws + OFF_HMT;

    const int blkid = blockIdx.x;
    const int grp  = blkid & 7;
    const int mem  = blkid >> 3;
    const int sgrp = mem & 7;
    const int dslc = mem >> 3;
    const int gm   = dslc * 8 + grp;
    unsigned* gslots = (unsigned*)ws + 256 + sgrp * 64;

    const int tid  = threadIdx.x;
    const int w    = tid >> 6;
    const int lane = tid & 63;
    const int b    = lane & 15;
    const int kc   = lane >> 4;
    const int dcol = grp * 64 + dslc * 16 + w;
    const int bgl  = sgrp * 16 + b;
    const int row0 = sgrp * 16;
    const int fcol = grp * 16 + dslc * 4 + (w & 3);
    const int gid  = blkid * NTHR + tid;

    pack_wsum(ws + OFF_F_WSUM, eW1, eU1, gid);
    pack_wdeca_p(ws + OFF_F_WDECA, dU0, dW0, dw, gid);
    if (gid < ND) {
        float acc = db0[gid];
        for (int j = 0; j < Fsz; ++j) acc += db_[j] * dW0[(size_t)j * ND + gid];
        (ws + OFF_F_BF)[gid] = acc;
    }
    if (gid < Dsz * Fsz) {
        const int f = gid >> 9, k = gid & 511;
        (ws + OFF_F_DWT)[(size_t)f * Dsz + k] = dw[(size_t)k * Fsz + f];
    }
    const float* pWSUM = ws + OFF_F_WSUM;
    const float* pWDECA = ws + OFF_F_WDECA;
    const float* pBF = ws + OFF_F_BF;
    const float* pDWT = ws + OFF_F_DWT;
    gbar_all(fslots, blkid, 1);

    unsigned ep = 0;
    int cur = 0;
    float c_car = 0.f;

    for (int t = 0; t < Tsz; ++t) {
        stage_vec(XL, 644, 0, enc_in + (size_t)t * Fsz, row0, Tsz * Fsz, 128, 5);
        __syncthreads();
        float4 z = make_float4(0.f, 0.f, 0.f, 0.f);
        acc_segS(z, XL + b * 644 + kc * 32, eW0, kc * 32, 32, dcol);
        wait_grp(gslots, ep);
        stage_coh_T(XL, 644, 128, HT[cur], row0);
        __syncthreads();
        acc_segS(z, XL + b * 644 + 128 + kc * 128, eU0, kc * 128, 128, dcol);
        reduce4(z);
        float c1 = 0.f;
        if (lane < 16) {
            float h2 = lstm_fin(z, eb0, dcol, c_car, c1);
            st_coh(&HMT[(size_t)dcol * Bsz + bgl], h2);
        }
        arrive(&gslots[gm], ++ep);
        wait_grp(gslots, ep);
        stage_coh_T(XL, 516, 0, HMT, row0);
        __syncthreads();
        z = make_float4(0.f, 0.f, 0.f, 0.f);
        {
            const float4* wp = (const float4*)pWSUM + (size_t)dcol * 512 + kc * 128;
            const float* xp = XL + b * 516 + kc * 128;
            #pragma unroll 4
            for (int j = 0; j < 128; j += 4) {
                float4 x4 = *(const float4*)(xp + j);
                float4 w0 = wp[j], w1 = wp[j + 1], w2 = wp[j + 2], w3 = wp[j + 3];
                z.x += x4.x*w0.x + x4.y*w1.x + x4.z*w2.x + x4.w*w3.x;
                z.y += x4.x*w0.y + x4.y*w1.y + x4.z*w2.y + x4.w*w3.y;
                z.z += x4.x*w0.z + x4.y*w1.z + x4.z*w2.z + x4.w*w3.z;
                z.w += x4.x*w0.w + x4.y*w1.w + x4.z*w2.w + x4.w*w3.w;
            }
        }
        reduce4(z);
        if (lane < 16) {
            float c2;
            float h2 = lstm_fin(z, eb1, dcol, c1, c2);
            c_car = c2;
            st_coh(&HT[cur ^ 1][(size_t)dcol * Bsz + bgl], h2);
        }
        arrive(&gslots[gm], ++ep);
        cur ^= 1;
    }

    stage_vec(XL, 644, 0, dec_in, row0, Tsz * Fsz, 128, 5);
    __syncthreads();
    {
        float4 z = make_float4(0.f, 0.f, 0.f, 0.f);
        acc_segS(z, XL + b * 644 + kc * 32, dW0, kc * 32, 32, dcol);
        wait_grp(gslots, ep);
        stage_coh_T(XL, 644, 128, HT[cur], row0);
        __syncthreads();
        acc_segS(z, XL + b * 644 + 128 + kc * 128, dU0, kc * 128, 128, dcol);
        reduce4(z);
        if (lane < 16) {
            float cd;
            float h2 = lstm_fin(z, db0, dcol, c_car, cd);
            st_coh(&HMT[(size_t)dcol * Bsz + bgl], h2);
        }
        arrive(&gslots[gm], ++ep);
    }
    wait_grp(gslots, ep);
    stage_coh_T(XL, 1028, 0, HT[cur], row0);
    stage_coh_T(XL, 1028, 512, HMT, row0);
    __syncthreads();
    {
        float4 z = make_float4(0.f, 0.f, 0.f, 0.f);
        acc_segS(z, XL + b * 1028 + kc * 128, dU1, kc * 128, 128, dcol);
        acc_segS(z, XL + b * 1028 + 512 + kc * 128, dW1, kc * 128, 128, dcol);
        reduce4(z);
        if (lane < 16) {
            float c2;
            float h2 = lstm_fin(z, db1, dcol, c_car, c2);
            c_car = c2;
            st_coh(&HT[cur ^ 1][(size_t)dcol * Bsz + bgl], h2);
        }
    }
    arrive(&gslots[gm], ++ep);
    cur ^= 1;

    for (int t = 1; t < Tsz; ++t) {
        const int tt = Tsz - t;
        wait_grp(gslots, ep);
        stage_coh_T(XL, 1028, 0, HT[cur], row0);
        __syncthreads();
        {
            float4 z = make_float4(0.f, 0.f, 0.f, 0.f);
            const float4* wp = (const float4*)pWDECA + (size_t)dcol * 512 + kc * 128;
            const float* xp = XL + b * 1028 + kc * 128;
            #pragma unroll 4
            for (int j = 0; j < 128; j += 4) {
                float4 x4 = *(const float4*)(xp + j);
                float4 w0 = wp[j], w1 = wp[j + 1], w2 = wp[j + 2], w3 = wp[j + 3];
                z.x += x4.x*w0.x + x4.y*w1.x + x4.z*w2.x + x4.w*w3.x;
                z.y += x4.x*w0.y + x4.y*w1.y + x4.z*w2.y + x4.w*w3.y;
                z.z += x4.x*w0.z + x4.y*w1.z + x4.z*w2.z + x4.w*w3.z;
                z.w += x4.x*w0.w + x4.y*w1.w + x4.z*w2.w + x4.w*w3.w;
            }
            reduce4(z);
            out_part(XL, 1028, ORED, b, kc, w, fcol, pDWT);
            if (lane < 16) {
                float cd;
                float h2 = lstm_fin(z, pBF, dcol, c_car, cd);
                st_coh(&HMT[(size_t)dcol * Bsz + bgl], h2);
            }
        }
        arrive(&gslots[gm], ++ep);
        if (tid < 64) {
            const int bb = tid >> 2, ff = tid & 3;
            const int fc = grp * 16 + dslc * 4 + ff;
            const float* r = ORED + bb * 16 + ff * 4;
            float s = r[0] + r[1] + r[2] + r[3] + db_[fc];
            out[((size_t)(row0 + bb) * Tsz + tt) * Fsz + fc] = s;
        }
        wait_grp(gslots, ep);
        stage_coh_T(XL, 1028, 512, HMT, row0);
        __syncthreads();
        {
            float4 z = make_float4(0.f, 0.f, 0.f, 0.f);
            acc_segS(z, XL + b * 1028 + kc * 128, dU1, kc * 128, 128, dcol);
            acc_segS(z, XL + b * 1028 + 512 + kc * 128, dW1, kc * 128, 128, dcol);
            reduce4(z);
            if (lane < 16) {
                float c2;
                float h2 = lstm_fin(z, db1, dcol, c_car, c2);
                c_car = c2;
                st_coh(&HT[cur ^ 1][(size_t)dcol * Bsz + bgl], h2);
            }
        }
        arrive(&gslots[gm], ++ep);
        cur ^= 1;
    }

    wait_grp(gslots, ep);
    stage_coh_T(XL, 516, 0, HT[cur], row0);
    __syncthreads();
    out_part(XL, 516, ORED, b, kc, w, fcol, pDWT);
    __syncthreads();
    if (tid < 64) {
        const int bb = tid >> 2, ff = tid & 3;
        const int fc = grp * 16 + dslc * 4 + ff;
        const float* r = ORED + bb * 16 + ff * 4;
        float s = r[0] + r[1] + r[2] + r[3] + db_[fc];
        out[((size_t)(row0 + bb) * Tsz + 0) * Fsz + fc] = s;
    }
}

extern "C" void kernel_launch(void* const* d_in, const int* in_sizes, int n_in,
                              void* d_out, int out_size, void* d_ws, size_t ws_size,
                              hipStream_t stream) {
    (void)in_sizes; (void)n_in; (void)out_size;
    const float* enc_in = (const float*)d_in[0];
    const float* dec_in = (const float*)d_in[1];
    const float* eW0 = (const float*)d_in[2];
    const float* eU0 = (const float*)d_in[3];
    const float* eb0 = (const float*)d_in[4];
    const float* eW1 = (const float*)d_in[5];
    const float* eU1 = (const float*)d_in[6];
    const float* eb1 = (const float*)d_in[7];
    const float* dW0 = (const float*)d_in[8];
    const float* dU0 = (const float*)d_in[9];
    const float* db0 = (const float*)d_in[10];
    const float* dW1 = (const float*)d_in[11];
    const float* dU1 = (const float*)d_in[12];
    const float* db1 = (const float*)d_in[13];
    const float* dw  = (const float*)d_in[14];
    const float* db_ = (const float*)d_in[15];
    float* out = (float*)d_out;
    float* ws = (float*)d_ws;

    // zero: full-grid slots + 16x32 chain slots + HT0 (initial h = 0)
    hipMemsetAsync(d_ws, 0, (size_t)(OFF_HT0 + Dsz * Bsz) * sizeof(float), stream);

    if (ws_size >= (size_t)WS_PACKED_FLOATS * sizeof(float))
        lstm_ae_v12<<<NBLK, NTHR, 0, stream>>>(
            enc_in, dec_in, eW0, eU0, eb0, eW1, eU1, eb1,
            dW0, dU0, db0, dW1, dU1, db1, dw, db_, out, ws);
    else
        lstm_ae_fb<<<NBLK, NTHR, 0, stream>>>(
            enc_in, dec_in, eW0, eU0, eb0, eW1, eU1, eb1,
            dW0, dU0, db0, dW1, dU1, db1, dw, db_, out, ws);
}

// Round 8
// 7264.331 us; speedup vs baseline: 2.7502x; 2.6965x over previous
//
#include <hip/hip_runtime.h>

// =====================================================================
// LSTM autoencoder v13 == v10 exact revert (bisect conclusion).
//
// Bisect history:
//  v10 (dual-chain + halved-shfl/DPP reduce):       7.25 ms, FETCH 0.88 GB
//  v11 (+wide poll, +chunk0 reg prefetch):         20.0 ms, FETCH 27 GB
//  v12 (wave0 poll restored, prefetch kept):       19.6 ms, FETCH 24 GB
// => The REGISTER PREFETCH was the poison: P[8] (32 VGPR) live across
//    the atomic-spin wait region spills to scratch (read:write ~2:1 in
//    HBM counters). VGPR_Count stays 64 (allocation granule) — spills
//    are visible only via FETCH/WRITE_SIZE.
// RULES (ledger): (1) no register arrays live across spin-wait regions;
// (2) spin-poll only from wave0 (agent-scope poll loads are HBM
// traffic); (3) spill tripwire = FETCH/WRITE_SIZE, not VGPR_Count.
//
// This file is v10 byte-equivalent modulo this comment block.
// =====================================================================

#define Bsz 128
#define Tsz 128
#define Fsz 128
#define Dsz 512
#define ND  2048
#define NBLK 256
#define NTHR 1024

// ---- ws layout (float offsets) ----
#define OFF_HT0  1024
#define OFF_HT1  (OFF_HT0 + Dsz*Bsz)
#define OFF_HMT  (OFF_HT1 + Dsz*Bsz)
#define OFF_WEND (OFF_HMT + Dsz*Bsz)
// packed weights (gate-interleaved float4: Wp4[dcol*K + k] = {i,f,g,o})
#define OFF_P_EW0   OFF_WEND
#define OFF_P_EU0   (OFF_P_EW0 + Fsz*ND)
#define OFF_P_WSUM  (OFF_P_EU0 + Dsz*ND)
#define OFF_P_WDECA (OFF_P_WSUM + Dsz*ND)
#define OFF_P_DW0   (OFF_P_WDECA + Dsz*ND)
#define OFF_P_DU0   (OFF_P_DW0 + Fsz*ND)
#define OFF_P_DW1   (OFF_P_DU0 + Dsz*ND)
#define OFF_P_DU1   (OFF_P_DW1 + Dsz*ND)
#define OFF_P_BF    (OFF_P_DU1 + Dsz*ND)
#define OFF_P_DWT   (OFF_P_BF + ND)
#define WS_PACKED_FLOATS (OFF_P_DWT + Dsz*Fsz)
// fallback layout
#define OFF_F_WSUM  OFF_WEND
#define OFF_F_WDECA (OFF_F_WSUM + Dsz*ND)
#define OFF_F_BF    (OFF_F_WDECA + Dsz*ND)
#define OFF_F_DWT   (OFF_F_BF + ND)
#define WS_FALLBACK_FLOATS (OFF_F_DWT + Dsz*Fsz)

#define NR 12   // LDS row stride: 8 data + 4 pad floats (16B aligned)

__device__ __forceinline__ float sigf(float x) {
    return 1.0f / (1.0f + __expf(-x));
}
__device__ __forceinline__ float ld_coh(const float* p) {
    return __hip_atomic_load((float*)p, __ATOMIC_RELAXED, __HIP_MEMORY_SCOPE_AGENT);
}
__device__ __forceinline__ void st_coh(float* p, float v) {
    __hip_atomic_store(p, v, __ATOMIC_RELAXED, __HIP_MEMORY_SCOPE_AGENT);
}

// ---- split group barrier (32 members, per-chain slot arrays) ----
__device__ __forceinline__ void arrive(unsigned* slot, unsigned ep) {
    __syncthreads();
    if (threadIdx.x == 0)
        __hip_atomic_store(slot, ep, __ATOMIC_RELEASE, __HIP_MEMORY_SCOPE_AGENT);
}
__device__ __forceinline__ void wait_grp(unsigned* gslots, unsigned ep) {
    if (threadIdx.x < 64) {
        for (;;) {
            unsigned v = (threadIdx.x < 32)
                ? __hip_atomic_load(&gslots[threadIdx.x], __ATOMIC_RELAXED,
                                    __HIP_MEMORY_SCOPE_AGENT)
                : ep;
            if (__all(v >= ep)) break;
            __builtin_amdgcn_s_sleep(1);
        }
    }
    __syncthreads();
}
__device__ __forceinline__ void gbar_all(unsigned* slots, int blkid, unsigned ep) {
    __syncthreads();
    if (threadIdx.x == 0) {
        __threadfence();
        __hip_atomic_store(&slots[blkid], ep, __ATOMIC_RELEASE,
                           __HIP_MEMORY_SCOPE_AGENT);
    }
    if (threadIdx.x < 64) {
        for (;;) {
            unsigned mn = ~0u;
            #pragma unroll
            for (int q = 0; q < 4; ++q) {
                unsigned v = __hip_atomic_load(&slots[threadIdx.x * 4 + q],
                                               __ATOMIC_RELAXED, __HIP_MEMORY_SCOPE_AGENT);
                mn = min(mn, v);
            }
            if (__all(mn >= ep)) break;
            __builtin_amdgcn_s_sleep(1);
        }
        if (threadIdx.x == 0) __threadfence();
    }
    __syncthreads();
}

// ---- P0 packing (identical to v6..v10) ----
__device__ void pack_gate(float* dst, const float* src, int K, int kshift, int gid) {
    const int total = K * Dsz;
    for (int u = gid; u < total; u += NBLK * NTHR) {
        const int dd = u >> kshift;
        const int k = u & (K - 1);
        const float* sp = src + (size_t)k * ND + dd;
        ((float4*)dst)[u] = make_float4(sp[0], sp[Dsz], sp[2 * Dsz], sp[3 * Dsz]);
    }
}
__device__ void pack_wsum(float* dst, const float* a, const float* bsrc, int gid) {
    for (int u = gid; u < Dsz * Dsz; u += NBLK * NTHR) {
        const int dd = u >> 9, k = u & 511;
        const float* pa = a + (size_t)k * ND + dd;
        const float* pb = bsrc + (size_t)k * ND + dd;
        ((float4*)dst)[u] = make_float4(pa[0] + pb[0], pa[Dsz] + pb[Dsz],
                                        pa[2*Dsz] + pb[2*Dsz], pa[3*Dsz] + pb[3*Dsz]);
    }
}
__device__ void pack_wdeca_p(float* dst, const float* dU0, const float* dW0,
                             const float* dw, int gid) {
    for (int u = gid; u < Dsz * Dsz; u += NBLK * NTHR) {
        const int dd = u >> 9, k = u & 511;
        const float* pu = dU0 + (size_t)k * ND + dd;
        float a0 = pu[0], a1 = pu[Dsz], a2 = pu[2*Dsz], a3 = pu[3*Dsz];
        const float* dwr = dw + k * Fsz;
        for (int j = 0; j < Fsz; ++j) {
            const float wv = dwr[j];
            const float* dr = dW0 + (size_t)j * ND + dd;
            a0 += wv * dr[0]; a1 += wv * dr[Dsz];
            a2 += wv * dr[2*Dsz]; a3 += wv * dr[3*Dsz];
        }
        ((float4*)dst)[u] = make_float4(a0, a1, a2, a3);
    }
}

// =====================================================================
// ======================  v13 (= v10) kernel  =========================
// =====================================================================

// stage 512 h rows (8 samples) from transposed coherent buffer
__device__ __forceinline__ void stageH9(float* XL, const float* HTsrc, int sr, int rbase) {
    #pragma unroll
    for (int ii = 0; ii < 4; ++ii) {
        const int i = (int)threadIdx.x + ii * NTHR;
        const int r = i >> 3, bb = i & 7;
        XL[(rbase + r) * NR + bb] = ld_coh(HTsrc + (size_t)r * Bsz + sr + bb);
    }
}
// stage 128 x rows (8 samples), 1 elem/thread
__device__ __forceinline__ void stageX9(float* XL, const float* src, int sr, int rbase) {
    const int r = (int)threadIdx.x & 127, bb = (int)threadIdx.x >> 7;
    XL[(rbase + r) * NR + bb] = src[(size_t)(sr + bb) * (Tsz * Fsz) + r];
}

#define FMA16(A0,A1,A2,A3,x4,w4) \
    A0.x += x4.x*w4.x; A0.y += x4.x*w4.y; A0.z += x4.x*w4.z; A0.w += x4.x*w4.w; \
    A1.x += x4.y*w4.x; A1.y += x4.y*w4.y; A1.z += x4.y*w4.z; A1.w += x4.y*w4.w; \
    A2.x += x4.z*w4.x; A2.y += x4.z*w4.y; A2.z += x4.z*w4.z; A2.w += x4.z*w4.w; \
    A3.x += x4.w*w4.x; A3.y += x4.w*w4.y; A3.z += x4.w*w4.z; A3.w += x4.w*w4.w;

// consume NJ*32 K-rows: Wp pre-offset by koff; Xb pre-offset by
// (rowbase+koff)*NR + qb2*4. Row step per j = 32.
template<int NJ>
__device__ __forceinline__ void consTv(const float4* __restrict__ Wp,
        const float* __restrict__ Xb,
        float4& A0, float4& A1, float4& A2, float4& A3)
{
    #pragma unroll 8
    for (int j = 0; j < NJ; ++j) {
        const float4 x4 = *(const float4*)(Xb + j * (32 * NR));
        const float4 w4 = Wp[j * 32];
        FMA16(A0, A1, A2, A3, x4, w4)
    }
}

// ---- cheap cross-lane reduction ----
__device__ __forceinline__ float dppx1(float v) {   // xor 1
    return v + __int_as_float(__builtin_amdgcn_mov_dpp(
        __float_as_int(v), 0xB1, 0xf, 0xf, true));
}
__device__ __forceinline__ float dppx2(float v) {   // xor 2
    return v + __int_as_float(__builtin_amdgcn_mov_dpp(
        __float_as_int(v), 0x4E, 0xf, 0xf, true));
}
__device__ __forceinline__ float dpphm(float v) {   // i^7 within 8
    return v + __int_as_float(__builtin_amdgcn_mov_dpp(
        __float_as_int(v), 0x141, 0xf, 0xf, true));
}
#define HXCH(lo, hi, mask, cond) { \
    float s_ = (cond) ? (lo) : (hi); \
    float r_ = __shfl_xor(s_, mask); \
    if (cond) (hi) += r_; else (lo) += r_; }

__device__ __forceinline__ float4 redZ(float4 A0, float4 A1, float4 A2, float4 A3,
                                       bool khb, bool b3b)
{
    HXCH(A0.x, A2.x, 32, khb) HXCH(A0.y, A2.y, 32, khb)
    HXCH(A0.z, A2.z, 32, khb) HXCH(A0.w, A2.w, 32, khb)
    HXCH(A1.x, A3.x, 32, khb) HXCH(A1.y, A3.y, 32, khb)
    HXCH(A1.z, A3.z, 32, khb) HXCH(A1.w, A3.w, 32, khb)
    float4 B0, B1;
    B0.x = khb ? A2.x : A0.x; B0.y = khb ? A2.y : A0.y;
    B0.z = khb ? A2.z : A0.z; B0.w = khb ? A2.w : A0.w;
    B1.x = khb ? A3.x : A1.x; B1.y = khb ? A3.y : A1.y;
    B1.z = khb ? A3.z : A1.z; B1.w = khb ? A3.w : A1.w;
    HXCH(B0.x, B1.x, 8, b3b) HXCH(B0.y, B1.y, 8, b3b)
    HXCH(B0.z, B1.z, 8, b3b) HXCH(B0.w, B1.w, 8, b3b)
    float4 Z;
    Z.x = b3b ? B1.x : B0.x; Z.y = b3b ? B1.y : B0.y;
    Z.z = b3b ? B1.z : B0.z; Z.w = b3b ? B1.w : B0.w;
    Z.x = dppx1(Z.x); Z.y = dppx1(Z.y); Z.z = dppx1(Z.z); Z.w = dppx1(Z.w);
    Z.x = dppx2(Z.x); Z.y = dppx2(Z.y); Z.z = dppx2(Z.z); Z.w = dppx2(Z.w);
    Z.x = dpphm(Z.x); Z.y = dpphm(Z.y); Z.z = dpphm(Z.z); Z.w = dpphm(Z.w);
    return Z;
}

__device__ __forceinline__ float fin4b(float4 z, const float* bias, int dcol,
                                       float cprev, float& c2o) {
    float gi = sigf(z.x + bias[dcol]);
    float gf = sigf(z.y + bias[Dsz + dcol]);
    float gg = fmaxf(z.z + bias[2 * Dsz + dcol], 0.f);
    float go = sigf(z.w + bias[3 * Dsz + dcol]);
    float c2 = gf * cprev + gi * gg;
    c2o = c2;
    return go * fmaxf(c2, 0.f);
}

// fused dense-row partials for one chain: ORED[sample][ff*4+qk]
__device__ __forceinline__ void out_part9(const float* XL, const float* DWL, float* ORED,
                                          int xo, int koff, int wv,
                                          bool khb, bool b3b, bool own, int sown)
{
    const int ff = wv & 3, qk = wv >> 2;
    float o0 = 0.f, o1 = 0.f, o2 = 0.f, o3 = 0.f;
    const float* Xb = XL + qk * 128 * NR + xo;
    const float* Wb = DWL + ff * 512 + qk * 128 + koff;
    #pragma unroll
    for (int j = 0; j < 4; ++j) {
        const float4 x4 = *(const float4*)(Xb + j * (32 * NR));
        const float w = Wb[j * 32];
        o0 += x4.x * w; o1 += x4.y * w; o2 += x4.z * w; o3 += x4.w * w;
    }
    HXCH(o0, o2, 32, khb) HXCH(o1, o3, 32, khb)
    float p0 = khb ? o2 : o0;
    float p1 = khb ? o3 : o1;
    HXCH(p0, p1, 8, b3b)
    float o = b3b ? p1 : p0;
    o = dppx1(o); o = dppx2(o); o = dpphm(o);
    if (own) ORED[sown * 16 + ff * 4 + qk] = o;
}

__global__ void __launch_bounds__(NTHR, 1)
lstm_ae_v13(const float* enc_in, const float* dec_in,
            const float* eW0, const float* eU0, const float* eb0,
            const float* eW1, const float* eU1, const float* eb1,
            const float* dW0, const float* dU0, const float* db0,
            const float* dW1, const float* dU1, const float* db1,
            const float* dw, const float* db_, float* out, float* ws)
{
    __shared__ float XLA[1024 * NR];   // 48 KB chain A: h rows 0..511, x/hA rows 512+
    __shared__ float XLB[1024 * NR];   // 48 KB chain B
    __shared__ float DWL[4 * 512];     //  8 KB resident dwT slice (4 fcols)
    __shared__ float OREDA[128];
    __shared__ float OREDB[128];

    unsigned* fslots = (unsigned*)ws;
    float* HT[2] = { ws + OFF_HT0, ws + OFF_HT1 };
    float* HMT = ws + OFF_HMT;

    const int blkid = blockIdx.x;
    const int grp  = blkid & 7;       // XCD / dcol-slice owner
    const int mem  = blkid >> 3;
    const int sgrp = mem & 7;
    const int dslc = mem >> 3;
    const int gm   = dslc * 8 + grp;  // member id (0..31)
    const int chA  = sgrp * 2, chB = chA + 1;     // 16 chains, 32 slots each
    unsigned* gsA = (unsigned*)ws + 256 + chA * 32;
    unsigned* gsB = (unsigned*)ws + 256 + chB * 32;
    const int srA = sgrp * 16;        // chain A samples [srA, srA+8)
    const int srB = sgrp * 16 + 8;

    const int tid  = threadIdx.x;
    const int wv   = tid >> 6;
    const int lane = tid & 63;
    const int kh   = lane >> 5;          // K-half bit
    const int qb2  = (lane >> 4) & 1;    // sample quad (of 2)
    const int kc   = lane & 15;          // K interleave slot
    const int koff = kh * 16 + kc;       // K offset within 32-row step
    const int dcol = grp * 64 + dslc * 16 + wv;
    const int fcol0 = grp * 16 + dslc * 4;
    const int gid  = blkid * NTHR + tid;
    const bool khb = (kh != 0);
    const bool b3b = ((kc & 8) != 0);
    const bool own = ((kc & 7) == 0);    // one lane per owned sample
    const int sown = qb2 * 4 + kh * 2 + ((kc >> 3) & 1);
    const int xo   = koff * NR + qb2 * 4; // per-thread LDS read base

    // ---- P0 ----
    pack_gate(ws + OFF_P_EW0, eW0, Fsz, 7, gid);
    pack_gate(ws + OFF_P_EU0, eU0, Dsz, 9, gid);
    pack_wsum(ws + OFF_P_WSUM, eW1, eU1, gid);
    pack_wdeca_p(ws + OFF_P_WDECA, dU0, dW0, dw, gid);
    pack_gate(ws + OFF_P_DW0, dW0, Fsz, 7, gid);
    pack_gate(ws + OFF_P_DU0, dU0, Dsz, 9, gid);
    pack_gate(ws + OFF_P_DW1, dW1, Dsz, 9, gid);
    pack_gate(ws + OFF_P_DU1, dU1, Dsz, 9, gid);
    if (gid < ND) {
        float acc = db0[gid];
        for (int j = 0; j < Fsz; ++j) acc += db_[j] * dW0[(size_t)j * ND + gid];
        (ws + OFF_P_BF)[gid] = acc;
    }
    if (gid < Dsz * Fsz) {
        const int f = gid >> 9, k = gid & 511;
        (ws + OFF_P_DWT)[(size_t)f * Dsz + k] = dw[(size_t)k * Fsz + f];
    }
    gbar_all(fslots, blkid, 1);

    // resident dwT slice for this block's 4 fcols
    #pragma unroll
    for (int ii = 0; ii < 2; ++ii) {
        const int i = tid + ii * NTHR;
        DWL[i] = (ws + OFF_P_DWT)[(size_t)(fcol0 + (i >> 9)) * Dsz + (i & 511)];
    }
    __syncthreads();

    const float* pBF = ws + OFF_P_BF;
    const float4* W_EW0   = (const float4*)(ws + OFF_P_EW0)   + (size_t)dcol * 128 + koff;
    const float4* W_EU0   = (const float4*)(ws + OFF_P_EU0)   + (size_t)dcol * 512 + koff;
    const float4* W_WSUM  = (const float4*)(ws + OFF_P_WSUM)  + (size_t)dcol * 512 + koff;
    const float4* W_WDECA = (const float4*)(ws + OFF_P_WDECA) + (size_t)dcol * 512 + koff;
    const float4* W_DW0   = (const float4*)(ws + OFF_P_DW0)   + (size_t)dcol * 128 + koff;
    const float4* W_DU0   = (const float4*)(ws + OFF_P_DU0)   + (size_t)dcol * 512 + koff;
    const float4* W_DW1   = (const float4*)(ws + OFF_P_DW1)   + (size_t)dcol * 512 + koff;
    const float4* W_DU1   = (const float4*)(ws + OFF_P_DU1)   + (size_t)dcol * 512 + koff;

    unsigned epA = 0, epB = 0;
    int cur = 0;
    float cA = 0.f, cmA = 0.f, cB = 0.f, cmB = 0.f;
    const float4 Z4 = make_float4(0.f, 0.f, 0.f, 0.f);

    // ======================= encoder =======================
    for (int t = 0; t < Tsz; ++t) {
        stageX9(XLA, enc_in + (size_t)t * Fsz, srA, 512);
        stageX9(XLB, enc_in + (size_t)t * Fsz, srB, 512);
        __syncthreads();
        // ---- A L0 ----
        {
            float4 A0 = Z4, A1 = Z4, A2 = Z4, A3 = Z4;
            consTv<4>(W_EW0, XLA + 512 * NR + xo, A0, A1, A2, A3);
            wait_grp(gsA, epA);
            stageH9(XLA, HT[cur], srA, 0);
            __syncthreads();
            consTv<16>(W_EU0, XLA + xo, A0, A1, A2, A3);
            float4 Z = redZ(A0, A1, A2, A3, khb, b3b);
            if (own) {
                float cn; float h2 = fin4b(Z, eb0, dcol, cA, cn); cmA = cn;
                st_coh(&HMT[(size_t)dcol * Bsz + srA + sown], h2);
            }
            arrive(&gsA[gm], ++epA);
        }
        // ---- B L0 ----
        {
            float4 A0 = Z4, A1 = Z4, A2 = Z4, A3 = Z4;
            consTv<4>(W_EW0, XLB + 512 * NR + xo, A0, A1, A2, A3);
            wait_grp(gsB, epB);
            stageH9(XLB, HT[cur], srB, 0);
            __syncthreads();
            consTv<16>(W_EU0, XLB + xo, A0, A1, A2, A3);
            float4 Z = redZ(A0, A1, A2, A3, khb, b3b);
            if (own) {
                float cn; float h2 = fin4b(Z, eb0, dcol, cB, cn); cmB = cn;
                st_coh(&HMT[(size_t)dcol * Bsz + srB + sown], h2);
            }
            arrive(&gsB[gm], ++epB);
        }
        // ---- A L1 ----
        {
            wait_grp(gsA, epA);
            stageH9(XLA, HMT, srA, 0);
            __syncthreads();
            float4 A0 = Z4, A1 = Z4, A2 = Z4, A3 = Z4;
            consTv<16>(W_WSUM, XLA + xo, A0, A1, A2, A3);
            float4 Z = redZ(A0, A1, A2, A3, khb, b3b);
            if (own) {
                float cn; float h2 = fin4b(Z, eb1, dcol, cmA, cn); cA = cn;
                st_coh(&HT[cur ^ 1][(size_t)dcol * Bsz + srA + sown], h2);
            }
            arrive(&gsA[gm], ++epA);
        }
        // ---- B L1 ----
        {
            wait_grp(gsB, epB);
            stageH9(XLB, HMT, srB, 0);
            __syncthreads();
            float4 A0 = Z4, A1 = Z4, A2 = Z4, A3 = Z4;
            consTv<16>(W_WSUM, XLB + xo, A0, A1, A2, A3);
            float4 Z = redZ(A0, A1, A2, A3, khb, b3b);
            if (own) {
                float cn; float h2 = fin4b(Z, eb1, dcol, cmB, cn); cB = cn;
                st_coh(&HT[cur ^ 1][(size_t)dcol * Bsz + srB + sown], h2);
            }
            arrive(&gsB[gm], ++epB);
        }
        cur ^= 1;
    }

    // ======================= decoder t=0 =======================
    {
        stageX9(XLA, dec_in, srA, 512);
        stageX9(XLB, dec_in, srB, 512);
        __syncthreads();
        // A L0 (c discarded)
        {
            float4 A0 = Z4, A1 = Z4, A2 = Z4, A3 = Z4;
            consTv<4>(W_DW0, XLA + 512 * NR + xo, A0, A1, A2, A3);
            wait_grp(gsA, epA);
            stageH9(XLA, HT[cur], srA, 0);
            __syncthreads();
            consTv<16>(W_DU0, XLA + xo, A0, A1, A2, A3);
            float4 Z = redZ(A0, A1, A2, A3, khb, b3b);
            if (own) {
                float cd; float h2 = fin4b(Z, db0, dcol, cA, cd);
                st_coh(&HMT[(size_t)dcol * Bsz + srA + sown], h2);
            }
            arrive(&gsA[gm], ++epA);
        }
        // B L0
        {
            float4 A0 = Z4, A1 = Z4, A2 = Z4, A3 = Z4;
            consTv<4>(W_DW0, XLB + 512 * NR + xo, A0, A1, A2, A3);
            wait_grp(gsB, epB);
            stageH9(XLB, HT[cur], srB, 0);
            __syncthreads();
            consTv<16>(W_DU0, XLB + xo, A0, A1, A2, A3);
            float4 Z = redZ(A0, A1, A2, A3, khb, b3b);
            if (own) {
                float cd; float h2 = fin4b(Z, db0, dcol, cB, cd);
                st_coh(&HMT[(size_t)dcol * Bsz + srB + sown], h2);
            }
            arrive(&gsB[gm], ++epB);
        }
        // A L1: h_old (rows 0..511, still staged) @ dU1 + hA (rows 512+) @ dW1; old carry
        {
            wait_grp(gsA, epA);
            stageH9(XLA, HMT, srA, 512);
            __syncthreads();
            float4 A0 = Z4, A1 = Z4, A2 = Z4, A3 = Z4;
            consTv<16>(W_DU1, XLA + xo, A0, A1, A2, A3);
            consTv<16>(W_DW1, XLA + 512 * NR + xo, A0, A1, A2, A3);
            float4 Z = redZ(A0, A1, A2, A3, khb, b3b);
            if (own) {
                float cn; float h2 = fin4b(Z, db1, dcol, cA, cn); cA = cn;
                st_coh(&HT[cur ^ 1][(size_t)dcol * Bsz + srA + sown], h2);
            }
            arrive(&gsA[gm], ++epA);
        }
        // B L1
        {
            wait_grp(gsB, epB);
            stageH9(XLB, HMT, srB, 512);
            __syncthreads();
            float4 A0 = Z4, A1 = Z4, A2 = Z4, A3 = Z4;
            consTv<16>(W_DU1, XLB + xo, A0, A1, A2, A3);
            consTv<16>(W_DW1, XLB + 512 * NR + xo, A0, A1, A2, A3);
            float4 Z = redZ(A0, A1, A2, A3, khb, b3b);
            if (own) {
                float cn; float h2 = fin4b(Z, db1, dcol, cB, cn); cB = cn;
                st_coh(&HT[cur ^ 1][(size_t)dcol * Bsz + srB + sown], h2);
            }
            arrive(&gsB[gm], ++epB);
        }
        cur ^= 1;
    }

    // ======================= decoder t=1..127 =======================
    for (int t = 1; t < Tsz; ++t) {
        const int tt = Tsz - t;
        // ---- A L0 folded + fused out partials ----
        {
            wait_grp(gsA, epA);
            stageH9(XLA, HT[cur], srA, 0);
            __syncthreads();
            float4 A0 = Z4, A1 = Z4, A2 = Z4, A3 = Z4;
            consTv<16>(W_WDECA, XLA + xo, A0, A1, A2, A3);
            out_part9(XLA, DWL, OREDA, xo, koff, wv, khb, b3b, own, sown);
            float4 Z = redZ(A0, A1, A2, A3, khb, b3b);
            if (own) {
                float cd; float h2 = fin4b(Z, pBF, dcol, cA, cd);
                st_coh(&HMT[(size_t)dcol * Bsz + srA + sown], h2);
            }
            arrive(&gsA[gm], ++epA);
            if (tid < 32) {
                const int bb = tid >> 2, ff = tid & 3;
                const int fc = fcol0 + ff;
                const float* r = OREDA + bb * 16 + ff * 4;
                float s = r[0] + r[1] + r[2] + r[3] + db_[fc];
                out[((size_t)(srA + bb) * Tsz + tt) * Fsz + fc] = s;
            }
        }
        // ---- B L0 ----
        {
            wait_grp(gsB, epB);
            stageH9(XLB, HT[cur], srB, 0);
            __syncthreads();
            float4 A0 = Z4, A1 = Z4, A2 = Z4, A3 = Z4;
            consTv<16>(W_WDECA, XLB + xo, A0, A1, A2, A3);
            out_part9(XLB, DWL, OREDB, xo, koff, wv, khb, b3b, own, sown);
            float4 Z = redZ(A0, A1, A2, A3, khb, b3b);
            if (own) {
                float cd; float h2 = fin4b(Z, pBF, dcol, cB, cd);
                st_coh(&HMT[(size_t)dcol * Bsz + srB + sown], h2);
            }
            arrive(&gsB[gm], ++epB);
            if (tid < 32) {
                const int bb = tid >> 2, ff = tid & 3;
                const int fc = fcol0 + ff;
                const float* r = OREDB + bb * 16 + ff * 4;
                float s = r[0] + r[1] + r[2] + r[3] + db_[fc];
                out[((size_t)(srB + bb) * Tsz + tt) * Fsz + fc] = s;
            }
        }
        // ---- A L1 ----
        {
            wait_grp(gsA, epA);
            stageH9(XLA, HMT, srA, 512);
            __syncthreads();
            float4 A0 = Z4, A1 = Z4, A2 = Z4, A3 = Z4;
            consTv<16>(W_DU1, XLA + xo, A0, A1, A2, A3);
            consTv<16>(W_DW1, XLA + 512 * NR + xo, A0, A1, A2, A3);
            float4 Z = redZ(A0, A1, A2, A3, khb, b3b);
            if (own) {
                float cn; float h2 = fin4b(Z, db1, dcol, cA, cn); cA = cn;
                st_coh(&HT[cur ^ 1][(size_t)dcol * Bsz + srA + sown], h2);
            }
            arrive(&gsA[gm], ++epA);
        }
        // ---- B L1 ----
        {
            wait_grp(gsB, epB);
            stageH9(XLB, HMT, srB, 512);
            __syncthreads();
            float4 A0 = Z4, A1 = Z4, A2 = Z4, A3 = Z4;
            consTv<16>(W_DU1, XLB + xo, A0, A1, A2, A3);
            consTv<16>(W_DW1, XLB + 512 * NR + xo, A0, A1, A2, A3);
            float4 Z = redZ(A0, A1, A2, A3, khb, b3b);
            if (own) {
                float cn; float h2 = fin4b(Z, db1, dcol, cB, cn); cB = cn;
                st_coh(&HT[cur ^ 1][(size_t)dcol * Bsz + srB + sown], h2);
            }
            arrive(&gsB[gm], ++epB);
        }
        cur ^= 1;
    }

    // ======================= final out_127 -> row 0 =======================
    wait_grp(gsA, epA);
    stageH9(XLA, HT[cur], srA, 0);
    __syncthreads();
    out_part9(XLA, DWL, OREDA, xo, koff, wv, khb, b3b, own, sown);
    wait_grp(gsB, epB);
    stageH9(XLB, HT[cur], srB, 0);
    __syncthreads();
    out_part9(XLB, DWL, OREDB, xo, koff, wv, khb, b3b, own, sown);
    __syncthreads();
    if (tid < 64) {
        const int half = tid >> 5;            // 0 = chain A, 1 = chain B
        const int l = tid & 31;
        const int bb = l >> 2, ff = l & 3;
        const int fc = fcol0 + ff;
        const float* ored = half ? OREDB : OREDA;
        const int sr = half ? srB : srA;
        const float* r = ored + bb * 16 + ff * 4;
        float s = r[0] + r[1] + r[2] + r[3] + db_[fc];
        out[((size_t)(sr + bb) * Tsz + 0) * Fsz + fc] = s;
    }
}

// =====================================================================
// ======================  v8 fallback kernel  =========================
// =====================================================================

__device__ __forceinline__ void stage_vec(float* XL, int xstr, int dstoff,
        const float* src, int row0, int ld, int klen, int c4shift) {
    const int q = klen >> 2;
    const int n4 = q * 16;
    for (int i = threadIdx.x; i < n4; i += NTHR) {
        const int row = i >> c4shift;
        const int c4 = i & (q - 1);
        float4 v = *(const float4*)(src + (size_t)(row0 + row) * ld + (c4 << 2));
        *(float4*)(XL + row * xstr + dstoff + (c4 << 2)) = v;
    }
}
__device__ __forceinline__ void stage_coh_T(float* XL, int xstr, int dstoff,
        const float* HTsrc, int row0) {
    for (int i = threadIdx.x; i < Dsz * 16; i += NTHR) {
        const int d = i >> 4;
        const int bb = i & 15;
        XL[bb * xstr + dstoff + d] = ld_coh(HTsrc + (size_t)d * Bsz + row0 + bb);
    }
}
__device__ __forceinline__ void acc_segS(float4& z, const float* xp,
                                         const float* W, int kbase, int ksub, int dcol) {
    for (int j = 0; j < ksub; ++j) {
        const float x = xp[j];
        const float* wr = W + (size_t)(kbase + j) * ND + dcol;
        z.x += x * wr[0];
        z.y += x * wr[Dsz];
        z.z += x * wr[2 * Dsz];
        z.w += x * wr[3 * Dsz];
    }
}
__device__ __forceinline__ void reduce4(float4& z) {
    z.x += __shfl_xor(z.x, 16); z.x += __shfl_xor(z.x, 32);
    z.y += __shfl_xor(z.y, 16); z.y += __shfl_xor(z.y, 32);
    z.z += __shfl_xor(z.z, 16); z.z += __shfl_xor(z.z, 32);
    z.w += __shfl_xor(z.w, 16); z.w += __shfl_xor(z.w, 32);
}
__device__ __forceinline__ float lstm_fin(float4 z, const float* bias, int dcol,
                                          float cprev, float& c2out) {
    float gi = sigf(z.x + bias[dcol]);
    float gf = sigf(z.y + bias[Dsz + dcol]);
    float gg = fmaxf(z.z + bias[2 * Dsz + dcol], 0.f);
    float go = sigf(z.w + bias[3 * Dsz + dcol]);
    float c2 = gf * cprev + gi * gg;
    c2out = c2;
    return go * fmaxf(c2, 0.f);
}
__device__ __forceinline__ void out_part(const float* XL, int xstr, float* ORED,
                                         int b, int kc, int w, int fcol,
                                         const float* dwT) {
    const int q = w >> 2;
    const float* xp = XL + b * xstr + q * 128 + kc * 32;
    const float* wt = dwT + (size_t)fcol * Dsz + q * 128 + kc * 32;
    float acc = 0.f;
    #pragma unroll
    for (int j = 0; j < 32; j += 4) {
        float4 x4 = *(const float4*)(xp + j);
        float4 w4 = *(const float4*)(wt + j);
        acc += x4.x * w4.x + x4.y * w4.y + x4.z * w4.z + x4.w * w4.w;
    }
    acc += __shfl_xor(acc, 16); acc += __shfl_xor(acc, 32);
    if ((threadIdx.x & 63) < 16) ORED[b * 16 + (w & 3) * 4 + q] = acc;
}

__global__ void __launch_bounds__(NTHR, 1)
lstm_ae_fb(const float* enc_in, const float* dec_in,
           const float* eW0, const float* eU0, const float* eb0,
           const float* eW1, const float* eU1, const float* eb1,
           const float* dW0, const float* dU0, const float* db0,
           const float* dW1, const float* dU1, const float* db1,
           const float* dw, const float* db_, float* out, float* ws)
{
    __shared__ float XL[16 * 1028];
    __shared__ float ORED[256];

    unsigned* fslots = (unsigned*)ws;
    float* HT[2] = { ws + OFF_HT0, ws + OFF_HT1 };
    float* HMT = ws + OFF_HMT;

    const int blkid = blockIdx.x;
    const int grp  = blkid & 7;
    const int mem  = blkid >> 3;
    const int sgrp = mem & 7;
    const int dslc = mem >> 3;
    const int gm   = dslc * 8 + grp;
    unsigned* gslots = (unsigned*)ws + 256 + sgrp * 64;

    const int tid  = threadIdx.x;
    const int w    = tid >> 6;
    const int lane = tid & 63;
    const int b    = lane & 15;
    const int kc   = lane >> 4;
    const int dcol = grp * 64 + dslc * 16 + w;
    const int bgl  = sgrp * 16 + b;
    const int row0 = sgrp * 16;
    const int fcol = grp * 16 + dslc * 4 + (w & 3);
    const int gid  = blkid * NTHR + tid;

    pack_wsum(ws + OFF_F_WSUM, eW1, eU1, gid);
    pack_wdeca_p(ws + OFF_F_WDECA, dU0, dW0, dw, gid);
    if (gid < ND) {
        float acc = db0[gid];
        for (int j = 0; j < Fsz; ++j) acc += db_[j] * dW0[(size_t)j * ND + gid];
        (ws + OFF_F_BF)[gid] = acc;
    }
    if (gid < Dsz * Fsz) {
        const int f = gid >> 9, k = gid & 511;
        (ws + OFF_F_DWT)[(size_t)f * Dsz + k] = dw[(size_t)k * Fsz + f];
    }
    const float* pWSUM = ws + OFF_F_WSUM;
    const float* pWDECA = ws + OFF_F_WDECA;
    const float* pBF = ws + OFF_F_BF;
    const float* pDWT = ws + OFF_F_DWT;
    gbar_all(fslots, blkid, 1);

    unsigned ep = 0;
    int cur = 0;
    float c_car = 0.f;

    for (int t = 0; t < Tsz; ++t) {
        stage_vec(XL, 644, 0, enc_in + (size_t)t * Fsz, row0, Tsz * Fsz, 128, 5);
        __syncthreads();
        float4 z = make_float4(0.f, 0.f, 0.f, 0.f);
        acc_segS(z, XL + b * 644 + kc * 32, eW0, kc * 32, 32, dcol);
        wait_grp(gslots, ep);
        stage_coh_T(XL, 644, 128, HT[cur], row0);
        __syncthreads();
        acc_segS(z, XL + b * 644 + 128 + kc * 128, eU0, kc * 128, 128, dcol);
        reduce4(z);
        float c1 = 0.f;
        if (lane < 16) {
            float h2 = lstm_fin(z, eb0, dcol, c_car, c1);
            st_coh(&HMT[(size_t)dcol * Bsz + bgl], h2);
        }
        arrive(&gslots[gm], ++ep);
        wait_grp(gslots, ep);
        stage_coh_T(XL, 516, 0, HMT, row0);
        __syncthreads();
        z = make_float4(0.f, 0.f, 0.f, 0.f);
        {
            const float4* wp = (const float4*)pWSUM + (size_t)dcol * 512 + kc * 128;
            const float* xp = XL + b * 516 + kc * 128;
            #pragma unroll 4
            for (int j = 0; j < 128; j += 4) {
                float4 x4 = *(const float4*)(xp + j);
                float4 w0 = wp[j], w1 = wp[j + 1], w2 = wp[j + 2], w3 = wp[j + 3];
                z.x += x4.x*w0.x + x4.y*w1.x + x4.z*w2.x + x4.w*w3.x;
                z.y += x4.x*w0.y + x4.y*w1.y + x4.z*w2.y + x4.w*w3.y;
                z.z += x4.x*w0.z + x4.y*w1.z + x4.z*w2.z + x4.w*w3.z;
                z.w += x4.x*w0.w + x4.y*w1.w + x4.z*w2.w + x4.w*w3.w;
            }
        }
        reduce4(z);
        if (lane < 16) {
            float c2;
            float h2 = lstm_fin(z, eb1, dcol, c1, c2);
            c_car = c2;
            st_coh(&HT[cur ^ 1][(size_t)dcol * Bsz + bgl], h2);
        }
        arrive(&gslots[gm], ++ep);
        cur ^= 1;
    }

    stage_vec(XL, 644, 0, dec_in, row0, Tsz * Fsz, 128, 5);
    __syncthreads();
    {
        float4 z = make_float4(0.f, 0.f, 0.f, 0.f);
        acc_segS(z, XL + b * 644 + kc * 32, dW0, kc * 32, 32, dcol);
        wait_grp(gslots, ep);
        stage_coh_T(XL, 644, 128, HT[cur], row0);
        __syncthreads();
        acc_segS(z, XL + b * 644 + 128 + kc * 128, dU0, kc * 128, 128, dcol);
        reduce4(z);
        if (lane < 16) {
            float cd;
            float h2 = lstm_fin(z, db0, dcol, c_car, cd);
            st_coh(&HMT[(size_t)dcol * Bsz + bgl], h2);
        }
        arrive(&gslots[gm], ++ep);
    }
    wait_grp(gslots, ep);
    stage_coh_T(XL, 1028, 0, HT[cur], row0);
    stage_coh_T(XL, 1028, 512, HMT, row0);
    __syncthreads();
    {
        float4 z = make_float4(0.f, 0.f, 0.f, 0.f);
        acc_segS(z, XL + b * 1028 + kc * 128, dU1, kc * 128, 128, dcol);
        acc_segS(z, XL + b * 1028 + 512 + kc * 128, dW1, kc * 128, 128, dcol);
        reduce4(z);
        if (lane < 16) {
            float c2;
            float h2 = lstm_fin(z, db1, dcol, c_car, c2);
            c_car = c2;
            st_coh(&HT[cur ^ 1][(size_t)dcol * Bsz + bgl], h2);
        }
    }
    arrive(&gslots[gm], ++ep);
    cur ^= 1;

    for (int t = 1; t < Tsz; ++t) {
        const int tt = Tsz - t;
        wait_grp(gslots, ep);
        stage_coh_T(XL, 1028, 0, HT[cur], row0);
        __syncthreads();
        {
            float4 z = make_float4(0.f, 0.f, 0.f, 0.f);
            const float4* wp = (const float4*)pWDECA + (size_t)dcol * 512 + kc * 128;
            const float* xp = XL + b * 1028 + kc * 128;
            #pragma unroll 4
            for (int j = 0; j < 128; j += 4) {
                float4 x4 = *(const float4*)(xp + j);
                float4 w0 = wp[j], w1 = wp[j + 1], w2 = wp[j + 2], w3 = wp[j + 3];
                z.x += x4.x*w0.x + x4.y*w1.x + x4.z*w2.x + x4.w*w3.x;
                z.y += x4.x*w0.y + x4.y*w1.y + x4.z*w2.y + x4.w*w3.y;
                z.z += x4.x*w0.z + x4.y*w1.z + x4.z*w2.z + x4.w*w3.z;
                z.w += x4.x*w0.w + x4.y*w1.w + x4.z*w2.w + x4.w*w3.w;
            }
            reduce4(z);
            out_part(XL, 1028, ORED, b, kc, w, fcol, pDWT);
            if (lane < 16) {
                float cd;
                float h2 = lstm_fin(z, pBF, dcol, c_car, cd);
                st_coh(&HMT[(size_t)dcol * Bsz + bgl], h2);
            }
        }
        arrive(&gslots[gm], ++ep);
        if (tid < 64) {
            const int bb = tid >> 2, ff = tid & 3;
            const int fc = grp * 16 + dslc * 4 + ff;
            const float* r = ORED + bb * 16 + ff * 4;
            float s = r[0] + r[1] + r[2] + r[3] + db_[fc];
            out[((size_t)(row0 + bb) * Tsz + tt) * Fsz + fc] = s;
        }
        wait_grp(gslots, ep);
        stage_coh_T(XL, 1028, 512, HMT, row0);
        __syncthreads();
        {
            float4 z = make_float4(0.f, 0.f, 0.f, 0.f);
            acc_segS(z, XL + b * 1028 + kc * 128, dU1, kc * 128, 128, dcol);
            acc_segS(z, XL + b * 1028 + 512 + kc * 128, dW1, kc * 128, 128, dcol);
            reduce4(z);
            if (lane < 16) {
                float c2;
                float h2 = lstm_fin(z, db1, dcol, c_car, c2);
                c_car = c2;
                st_coh(&HT[cur ^ 1][(size_t)dcol * Bsz + bgl], h2);
            }
        }
        arrive(&gslots[gm], ++ep);
        cur ^= 1;
    }

    wait_grp(gslots, ep);
    stage_coh_T(XL, 516, 0, HT[cur], row0);
    __syncthreads();
    out_part(XL, 516, ORED, b, kc, w, fcol, pDWT);
    __syncthreads();
    if (tid < 64) {
        const int bb = tid >> 2, ff = tid & 3;
        const int fc = grp * 16 + dslc * 4 + ff;
        const float* r = ORED + bb * 16 + ff * 4;
        float s = r[0] + r[1] + r[2] + r[3] + db_[fc];
        out[((size_t)(row0 + bb) * Tsz + 0) * Fsz + fc] = s;
    }
}

extern "C" void kernel_launch(void* const* d_in, const int* in_sizes, int n_in,
                              void* d_out, int out_size, void* d_ws, size_t ws_size,
                              hipStream_t stream) {
    (void)in_sizes; (void)n_in; (void)out_size;
    const float* enc_in = (const float*)d_in[0];
    const float* dec_in = (const float*)d_in[1];
    const float* eW0 = (const float*)d_in[2];
    const float* eU0 = (const float*)d_in[3];
    const float* eb0 = (const float*)d_in[4];
    const float* eW1 = (const float*)d_in[5];
    const float* eU1 = (const float*)d_in[6];
    const float* eb1 = (const float*)d_in[7];
    const float* dW0 = (const float*)d_in[8];
    const float* dU0 = (const float*)d_in[9];
    const float* db0 = (const float*)d_in[10];
    const float* dW1 = (const float*)d_in[11];
    const float* dU1 = (const float*)d_in[12];
    const float* db1 = (const float*)d_in[13];
    const float* dw  = (const float*)d_in[14];
    const float* db_ = (const float*)d_in[15];
    float* out = (float*)d_out;
    float* ws = (float*)d_ws;

    // zero: full-grid slots + 16x32 chain slots + HT0 (initial h = 0)
    hipMemsetAsync(d_ws, 0, (size_t)(OFF_HT0 + Dsz * Bsz) * sizeof(float), stream);

    if (ws_size >= (size_t)WS_PACKED_FLOATS * sizeof(float))
        lstm_ae_v13<<<NBLK, NTHR, 0, stream>>>(
            enc_in, dec_in, eW0, eU0, eb0, eW1, eU1, eb1,
            dW0, dU0, db0, dW1, dU1, db1, dw, db_, out, ws);
    else
        lstm_ae_fb<<<NBLK, NTHR, 0, stream>>>(
            enc_in, dec_in, eW0, eU0, eb0, eW1, eU1, eb1,
            dW0, dU0, db0, dW1, dU1, db1, dw, db_, out, ws);
}